// Round 1
// baseline (1143.962 us; speedup 1.0000x reference)
//
#include <hip/hip_runtime.h>
#include <cstdint>

#define DEVI __device__ __forceinline__

constexpr int Bc = 4, Lc = 1024, DMc = 1024, Hc = 16, TDc = 8, Kc = 8, Dc = 64;
constexpr int NBL = Bc * Lc;               // 4096
constexpr int PAR = Hc * Dc * TDc * Kc;    // 65536 per param array

using f16x8 = __attribute__((ext_vector_type(8))) _Float16;
using s16x8 = __attribute__((ext_vector_type(8))) short;
using f32x4 = __attribute__((ext_vector_type(4))) float;

DEVI unsigned short f2bf(float x){
  union { float f; unsigned u; } v; v.f = x;
  return (unsigned short)((v.u + 0x7fffu + ((v.u >> 16) & 1u)) >> 16);
}

// LDS swizzle hook — identity this round (correctness baseline); flip to 1 later.
#define SWZ_ON 0
DEVI int swz(int row, int unit){
#if SWZ_ON
  return unit ^ (row & 7);
#else
  (void)row; return unit;
#endif
}

// ---------------- K0: precompute alpha = sqrt(log2e/2)/sigma ; WO -> bf16 ----
__global__ __launch_bounds__(256) void k0_alpha(
    const float* __restrict__ sQ, const float* __restrict__ sK, const float* __restrict__ sV,
    float* __restrict__ aQ, float* __restrict__ aK, float* __restrict__ aV)
{
  int i = blockIdx.x * 256 + threadIdx.x;
  if (i < PAR){
    const float c = 0.8493218002880191f; // sqrt(log2(e)/2)
    aQ[i] = c / sQ[i];
    aK[i] = c / sK[i];
    aV[i] = c / sV[i];
  }
}

__global__ __launch_bounds__(256) void k0_wo(const float* __restrict__ WO, unsigned short* __restrict__ WOb)
{
  int i = blockIdx.x * 256 + threadIdx.x;
  if (i < DMc * DMc) WOb[i] = f2bf(WO[i]);
}

// ---------------- K1: gaussian basis * P + gamma  (f32 out) ------------------
// grid (H, NBL/128), block 128.  thread = one (b,l) row; params are wave-uniform -> s_load.
__global__ __launch_bounds__(128) void k1_gauss(
    const float* __restrict__ P, const float* __restrict__ t,
    const float* __restrict__ mu0, const float* __restrict__ al0, const float* __restrict__ w0, const float* __restrict__ gm0,
    const float* __restrict__ mu1, const float* __restrict__ al1, const float* __restrict__ w1, const float* __restrict__ gm1,
    const float* __restrict__ mu2, const float* __restrict__ al2, const float* __restrict__ w2, const float* __restrict__ gm2,
    float* __restrict__ o0, float* __restrict__ o1, float* __restrict__ o2)
{
  __shared__ float gbuf[64 * 129];
  const int h = blockIdx.x, tile = blockIdx.y, tid = threadIdx.x;
  const int bl0 = tile * 128;

  float tv[8];
  #pragma unroll
  for (int j = 0; j < 8; ++j) tv[j] = t[(size_t)(bl0 + tid) * 8 + j];

  #pragma unroll 1
  for (int p = 0; p < 3; ++p){
    const float* mu = (p == 0) ? mu0 : (p == 1) ? mu1 : mu2;
    const float* al = (p == 0) ? al0 : (p == 1) ? al1 : al2;
    const float* wp = (p == 0) ? w0  : (p == 1) ? w1  : w2;
    const float* gm = (p == 0) ? gm0 : (p == 1) ? gm1 : gm2;
    float*       op = (p == 0) ? o0  : (p == 1) ? o1  : o2;

    #pragma unroll 1
    for (int d = 0; d < 64; ++d){
      const int base = (h * 64 + d) * 64;   // 64 (td,k) terms
      float g0 = 0.f, g1 = 0.f, g2 = 0.f, g3 = 0.f;
      #pragma unroll
      for (int td = 0; td < 8; ++td){
        const float tval = tv[td];
        #pragma unroll
        for (int k = 0; k < 8; ++k){
          const int idx = base + td * 8 + k;
          const float u = (tval - mu[idx]) * al[idx];   // 2^(-u^2) == exp(-(t-mu)^2/(2s^2))
          const float e = exp2f(-u * u);
          if ((k & 3) == 0)      g0 = fmaf(wp[idx], e, g0);
          else if ((k & 3) == 1) g1 = fmaf(wp[idx], e, g1);
          else if ((k & 3) == 2) g2 = fmaf(wp[idx], e, g2);
          else                   g3 = fmaf(wp[idx], e, g3);
        }
      }
      gbuf[d * 129 + tid] = (g0 + g1) + (g2 + g3);
    }
    __syncthreads();
    { // transposed write phase: lanes = d (coalesced global traffic)
      const int dl = tid & 63, hf = tid >> 6;
      const float gam = gm[h * 64 + dl];
      #pragma unroll 4
      for (int r = hf * 64; r < hf * 64 + 64; ++r){
        const float g  = gbuf[dl * 129 + r];
        const float ph = P[(size_t)(bl0 + r) * DMc + h * 64 + dl];
        op[(size_t)(bl0 + r) * DMc + h * 64 + dl] = fmaf(g, ph, gam);
      }
    }
    __syncthreads();
  }
}

// ---------------- K2: per-head projection (f32 vector GEMM, 64x64 W) ---------
// grid (H, NBL/64), block 256.  PROJ 0=Q (f16 split, scaled log2e/8), 1=K (f16 split), 2=V (bf16 transposed)
template<int PROJ>
__global__ __launch_bounds__(256) void k2_proj(
    const float* __restrict__ Xg, const float* __restrict__ W,
    _Float16* __restrict__ Ohi, _Float16* __restrict__ Olo,
    unsigned short* __restrict__ Obf)
{
  __shared__ __align__(16) float Al[64 * 64];
  __shared__ __align__(16) float Wl[64 * 64];
  const int h = blockIdx.x, tile = blockIdx.y, tid = threadIdx.x;
  const int bl0 = tile * 64;

  for (int i = tid; i < 1024; i += 256){        // A tile: 64 rows x 64 d (f32)
    const int row = i >> 4, c4 = i & 15;
    *(float4*)&Al[row * 64 + c4 * 4] =
        *(const float4*)&Xg[(size_t)(bl0 + row) * DMc + h * 64 + c4 * 4];
  }
  for (int i = tid; i < 1024; i += 256){        // W[h]: 64 d x 64 f (f32)
    const int row = i >> 4, c4 = i & 15;
    *(float4*)&Wl[row * 64 + c4 * 4] =
        *(const float4*)&W[((size_t)h * 64 + row) * 64 + c4 * 4];
  }
  __syncthreads();

  const int f = tid & 63, q = tid >> 6;
  for (int r = q * 16; r < q * 16 + 16; ++r){
    float acc = 0.f;
    #pragma unroll 8
    for (int d = 0; d < 64; ++d) acc = fmaf(Al[r * 64 + d], Wl[d * 64 + f], acc);

    const int m = bl0 + r;             // flat (b,l)
    const int b = m >> 10, l = m & 1023;
    if constexpr (PROJ == 0){
      acc *= 0.18033688011112042f;     // log2(e) / sqrt(D), folds softmax scale+base-2
      const _Float16 hi = (_Float16)acc;
      const _Float16 lo = (_Float16)(acc - (float)hi);
      const size_t o = (((size_t)b * Hc + h) * Lc + l) * 64 + f;
      Ohi[o] = hi; Olo[o] = lo;
    } else if constexpr (PROJ == 1){
      const _Float16 hi = (_Float16)acc;
      const _Float16 lo = (_Float16)(acc - (float)hi);
      const size_t o = (((size_t)b * Hc + h) * Lc + l) * 64 + (swz(l, f >> 3) << 3) + (f & 7);
      Ohi[o] = hi; Olo[o] = lo;
    } else {
      const int m0v = l & ~63, ml = l & 63;   // V transposed: [b][h][f][m]
      const size_t o = (((size_t)b * Hc + h) * 64 + f) * Lc + m0v + (swz(f, ml >> 3) << 3) + (ml & 7);
      Obf[o] = f2bf(acc);
    }
  }
}

// ---------------- K3: flash attention, f16-split QK^T + bf16 PV --------------
// grid (B*H, L/64), block 256 (4 waves, each owns 16 q-rows).
__global__ __launch_bounds__(256) void k3_attn(
    const _Float16* __restrict__ Qhi, const _Float16* __restrict__ Qlo,
    const _Float16* __restrict__ Khi, const _Float16* __restrict__ Klo,
    const unsigned short* __restrict__ Vt,
    unsigned short* __restrict__ AO)
{
  __shared__ __align__(16) _Float16 KhiL[64 * 64];
  __shared__ __align__(16) _Float16 KloL[64 * 64];
  __shared__ __align__(16) unsigned short VL[64 * 64];   // [f][m]
  __shared__ __align__(16) unsigned short PL[4][16 * 64];
  const int bh = blockIdx.x, qt = blockIdx.y;
  const int tid = threadIdx.x, wv = tid >> 6, lane = tid & 63;
  const int lrow = lane & 15, lgrp = lane >> 4;
  const size_t bhL = (size_t)bh * Lc;

  f16x8 qh[2], ql[2];
  {
    const int qrow = qt * 64 + wv * 16 + lrow;
    const _Float16* q1 = &Qhi[(bhL + qrow) * 64 + lgrp * 8];
    const _Float16* q2 = &Qlo[(bhL + qrow) * 64 + lgrp * 8];
    qh[0] = *(const f16x8*)q1; qh[1] = *(const f16x8*)(q1 + 32);
    ql[0] = *(const f16x8*)q2; ql[1] = *(const f16x8*)(q2 + 32);
  }

  f32x4 o[4] = {};
  float mrun[4], lrun[4];
  #pragma unroll
  for (int r = 0; r < 4; ++r){ mrun[r] = -1e30f; lrun[r] = 0.f; }

  for (int kt = 0; kt < 16; ++kt){
    __syncthreads();
    { // stage K hi/lo (contiguous 8KB) + V tile rows (reg-staged)
      const char* ks_ = (const char*)(Khi + (bhL + kt * 64) * 64);
      const char* ls_ = (const char*)(Klo + (bhL + kt * 64) * 64);
      const char* vs_ = (const char*)(Vt + (size_t)bh * 64 * Lc + kt * 64);
      const int i0 = tid, i1 = tid + 256;
      f16x8 a0 = *(const f16x8*)(ks_ + i0 * 16);
      f16x8 a1 = *(const f16x8*)(ks_ + i1 * 16);
      f16x8 b0 = *(const f16x8*)(ls_ + i0 * 16);
      f16x8 b1 = *(const f16x8*)(ls_ + i1 * 16);
      s16x8 c0 = *(const s16x8*)(vs_ + (i0 >> 3) * 2048 + (i0 & 7) * 16);
      s16x8 c1 = *(const s16x8*)(vs_ + (i1 >> 3) * 2048 + (i1 & 7) * 16);
      *(f16x8*)((char*)KhiL + i0 * 16) = a0;
      *(f16x8*)((char*)KhiL + i1 * 16) = a1;
      *(f16x8*)((char*)KloL + i0 * 16) = b0;
      *(f16x8*)((char*)KloL + i1 * 16) = b1;
      *(s16x8*)((char*)VL + i0 * 16) = c0;
      *(s16x8*)((char*)VL + i1 * 16) = c1;
    }
    __syncthreads();

    // S = Q.K^T in exp2 domain (3-pass f16 split: hh + lh + hl)
    f32x4 s[4] = {};
    #pragma unroll
    for (int tt = 0; tt < 4; ++tt){
      #pragma unroll
      for (int ks = 0; ks < 2; ++ks){
        const int m = tt * 16 + lrow;
        const int off = m * 128 + swz(m, ks * 4 + lgrp) * 16;
        f16x8 kh_ = *(const f16x8*)((const char*)KhiL + off);
        f16x8 kl_ = *(const f16x8*)((const char*)KloL + off);
        s[tt] = __builtin_amdgcn_mfma_f32_16x16x32_f16(qh[ks], kh_, s[tt], 0, 0, 0);
        s[tt] = __builtin_amdgcn_mfma_f32_16x16x32_f16(ql[ks], kh_, s[tt], 0, 0, 0);
        s[tt] = __builtin_amdgcn_mfma_f32_16x16x32_f16(qh[ks], kl_, s[tt], 0, 0, 0);
      }
    }

    // online softmax (rows l = lgrp*4 + r ; m spread across 16 lanes x 4 tiles)
    float sc[4];
    #pragma unroll
    for (int r = 0; r < 4; ++r){
      float v = fmaxf(fmaxf(s[0][r], s[1][r]), fmaxf(s[2][r], s[3][r]));
      v = fmaxf(v, __shfl_xor(v, 1));
      v = fmaxf(v, __shfl_xor(v, 2));
      v = fmaxf(v, __shfl_xor(v, 4));
      v = fmaxf(v, __shfl_xor(v, 8));
      const float mn = fmaxf(mrun[r], v);
      sc[r] = exp2f(mrun[r] - mn);
      mrun[r] = mn;
    }
    float rs[4] = {0.f, 0.f, 0.f, 0.f};
    unsigned short pb[4][4];
    #pragma unroll
    for (int tt = 0; tt < 4; ++tt){
      #pragma unroll
      for (int r = 0; r < 4; ++r){
        const float p = exp2f(s[tt][r] - mrun[r]);
        rs[r] += p;
        pb[tt][r] = f2bf(p);
      }
    }
    #pragma unroll
    for (int r = 0; r < 4; ++r){
      float v = rs[r];
      v += __shfl_xor(v, 1); v += __shfl_xor(v, 2); v += __shfl_xor(v, 4); v += __shfl_xor(v, 8);
      lrun[r] = lrun[r] * sc[r] + v;
      o[0][r] *= sc[r]; o[1][r] *= sc[r]; o[2][r] *= sc[r]; o[3][r] *= sc[r];
    }

    // P -> per-wave LDS (bf16), then PV MFMA (no barrier needed: wave-private)
    unsigned short* pw = (unsigned short*)PL[wv];
    #pragma unroll
    for (int tt = 0; tt < 4; ++tt){
      const int m = tt * 16 + lrow;
      #pragma unroll
      for (int r = 0; r < 4; ++r){
        const int l = lgrp * 4 + r;
        *(unsigned short*)((char*)pw + l * 128 + swz(l, m >> 3) * 16 + (m & 7) * 2) = pb[tt][r];
      }
    }
    #pragma unroll
    for (int ks = 0; ks < 2; ++ks){
      const int poff = lrow * 128 + swz(lrow, ks * 4 + lgrp) * 16;
      s16x8 pa = *(const s16x8*)((const char*)pw + poff);
      #pragma unroll
      for (int t2 = 0; t2 < 4; ++t2){
        const int f = t2 * 16 + lrow;
        const int voff = f * 128 + swz(f, ks * 4 + lgrp) * 16;
        s16x8 vb = *(const s16x8*)((const char*)VL + voff);
        o[t2] = __builtin_amdgcn_mfma_f32_16x16x32_bf16(pa, vb, o[t2], 0, 0, 0);
      }
    }
  }

  const int b = bh >> 4, hh = bh & 15;
  #pragma unroll
  for (int r = 0; r < 4; ++r){
    const float inv = 1.0f / lrun[r];
    const int l = qt * 64 + wv * 16 + lgrp * 4 + r;
    #pragma unroll
    for (int t2 = 0; t2 < 4; ++t2){
      const int f = t2 * 16 + lrow;
      AO[((size_t)(b * Lc + l)) * DMc + hh * 64 + f] = f2bf(o[t2][r] * inv);
    }
  }
}

// ---------------- K4: out = attn @ W_O^T + b  (bf16 MFMA GEMM, f32 out) ------
// grid (NBL/128, DM/128), block 256 (2x2 waves, each 64x64).
__global__ __launch_bounds__(256) void k4_out(
    const unsigned short* __restrict__ A, const unsigned short* __restrict__ Bw,
    const float* __restrict__ bias, float* __restrict__ out)
{
  __shared__ __align__(16) unsigned short Asl[128 * 64];
  __shared__ __align__(16) unsigned short Bsl[128 * 64];
  const int mt = blockIdx.x, nt = blockIdx.y;
  const int tid = threadIdx.x, wv = tid >> 6, lane = tid & 63;
  const int wr = wv >> 1, wc = wv & 1, lrow = lane & 15, lgrp = lane >> 4;
  f32x4 acc[4][4] = {};
  const char* abase = (const char*)A  + (size_t)mt * 128 * 2048;
  const char* bbase = (const char*)Bw + (size_t)nt * 128 * 2048;

  for (int kt = 0; kt < 16; ++kt){
    __syncthreads();
    #pragma unroll
    for (int q = 0; q < 4; ++q){
      const int i = q * 256 + tid, row = i >> 3, u = i & 7;
      s16x8 av = *(const s16x8*)(abase + (size_t)row * 2048 + kt * 128 + u * 16);
      s16x8 bv = *(const s16x8*)(bbase + (size_t)row * 2048 + kt * 128 + u * 16);
      *(s16x8*)((char*)Asl + row * 128 + swz(row, u) * 16) = av;
      *(s16x8*)((char*)Bsl + row * 128 + swz(row, u) * 16) = bv;
    }
    __syncthreads();
    #pragma unroll
    for (int ks = 0; ks < 2; ++ks){
      s16x8 af[4], bf[4];
      #pragma unroll
      for (int i4 = 0; i4 < 4; ++i4){
        const int row = wr * 64 + i4 * 16 + lrow;
        af[i4] = *(const s16x8*)((const char*)Asl + row * 128 + swz(row, ks * 4 + lgrp) * 16);
        const int col = wc * 64 + i4 * 16 + lrow;
        bf[i4] = *(const s16x8*)((const char*)Bsl + col * 128 + swz(col, ks * 4 + lgrp) * 16);
      }
      #pragma unroll
      for (int i4 = 0; i4 < 4; ++i4)
        #pragma unroll
        for (int j4 = 0; j4 < 4; ++j4)
          acc[i4][j4] = __builtin_amdgcn_mfma_f32_16x16x32_bf16(af[i4], bf[j4], acc[i4][j4], 0, 0, 0);
    }
  }
  #pragma unroll
  for (int i4 = 0; i4 < 4; ++i4)
    #pragma unroll
    for (int j4 = 0; j4 < 4; ++j4){
      const int col = nt * 128 + wc * 64 + j4 * 16 + lrow;
      const float bb = bias[col];
      #pragma unroll
      for (int r = 0; r < 4; ++r){
        const int row = mt * 128 + wr * 64 + i4 * 16 + lgrp * 4 + r;
        out[(size_t)row * DMc + col] = acc[i4][j4][r] + bb;
      }
    }
}

// ---------------- launch -----------------------------------------------------
extern "C" void kernel_launch(void* const* d_in, const int* in_sizes, int n_in,
                              void* d_out, int out_size, void* d_ws, size_t ws_size,
                              hipStream_t stream)
{
  const float* P   = (const float*)d_in[0];
  const float* t   = (const float*)d_in[1];
  const float* muQ = (const float*)d_in[2];
  const float* sgQ = (const float*)d_in[3];
  const float* wQ  = (const float*)d_in[4];
  const float* gQ  = (const float*)d_in[5];
  const float* WQ  = (const float*)d_in[6];
  const float* muK = (const float*)d_in[7];
  const float* sgK = (const float*)d_in[8];
  const float* wK  = (const float*)d_in[9];
  const float* gK  = (const float*)d_in[10];
  const float* WK  = (const float*)d_in[11];
  const float* muV = (const float*)d_in[12];
  const float* sgV = (const float*)d_in[13];
  const float* wV  = (const float*)d_in[14];
  const float* gV  = (const float*)d_in[15];
  const float* WV  = (const float*)d_in[16];
  const float* WO  = (const float*)d_in[17];
  const float* WOb = (const float*)d_in[18];

  char* w = (char*)d_ws;
  auto take = [&](size_t bytes) -> char* {
    char* p = w; w += (bytes + 255) & ~(size_t)255; return p;
  };
  float* aQ = (float*)take((size_t)PAR * 4);
  float* aK = (float*)take((size_t)PAR * 4);
  float* aV = (float*)take((size_t)PAR * 4);
  float* Qg = (float*)take((size_t)NBL * DMc * 4);
  float* Kg = (float*)take((size_t)NBL * DMc * 4);
  float* Vg = (float*)take((size_t)NBL * DMc * 4);
  _Float16* Qhi = (_Float16*)take((size_t)NBL * DMc * 2);
  _Float16* Qlo = (_Float16*)take((size_t)NBL * DMc * 2);
  _Float16* Khi = (_Float16*)take((size_t)NBL * DMc * 2);
  _Float16* Klo = (_Float16*)take((size_t)NBL * DMc * 2);
  unsigned short* Vt    = (unsigned short*)take((size_t)NBL * DMc * 2);
  unsigned short* AO    = (unsigned short*)take((size_t)NBL * DMc * 2);
  unsigned short* WOb16 = (unsigned short*)take((size_t)DMc * DMc * 2);
  if ((size_t)(w - (char*)d_ws) > ws_size) return;  // insufficient scratch: bail

  k0_alpha<<<PAR / 256, 256, 0, stream>>>(sgQ, sgK, sgV, aQ, aK, aV);
  k0_wo<<<DMc * DMc / 256, 256, 0, stream>>>(WO, WOb16);
  k1_gauss<<<dim3(Hc, NBL / 128), 128, 0, stream>>>(P, t,
      muQ, aQ, wQ, gQ,  muK, aK, wK, gK,  muV, aV, wV, gV,  Qg, Kg, Vg);
  k2_proj<0><<<dim3(Hc, NBL / 64), 256, 0, stream>>>(Qg, WQ, Qhi, Qlo, nullptr);
  k2_proj<1><<<dim3(Hc, NBL / 64), 256, 0, stream>>>(Kg, WK, Khi, Klo, nullptr);
  k2_proj<2><<<dim3(Hc, NBL / 64), 256, 0, stream>>>(Vg, WV, nullptr, nullptr, Vt);
  k3_attn<<<dim3(Bc * Hc, Lc / 64), 256, 0, stream>>>(Qhi, Qlo, Khi, Klo, Vt, AO);
  k4_out<<<dim3(NBL / 128, DMc / 128), 256, 0, stream>>>(AO, WOb16, WOb, (float*)d_out);
}

// Round 2
// 571.349 us; speedup vs baseline: 2.0022x; 2.0022x over previous
//
#include <hip/hip_runtime.h>
#include <cstdint>

#define DEVI __device__ __forceinline__

constexpr int Bc = 4, Lc = 1024, DMc = 1024, Hc = 16, TDc = 8, Kc = 8, Dc = 64;
constexpr int NBL = Bc * Lc;               // 4096
constexpr int PAR = Hc * Dc * TDc * Kc;    // 65536 per param array

using f16x8 = __attribute__((ext_vector_type(8))) _Float16;
using s16x8 = __attribute__((ext_vector_type(8))) short;
using f32x4 = __attribute__((ext_vector_type(4))) float;

DEVI unsigned short f2bf(float x){
  union { float f; unsigned u; } v; v.f = x;
  return (unsigned short)((v.u + 0x7fffu + ((v.u >> 16) & 1u)) >> 16);
}

// LDS swizzle hook — identity (correctness baseline); flip to 1 later.
#define SWZ_ON 0
DEVI int swz(int row, int unit){
#if SWZ_ON
  return unit ^ (row & 7);
#else
  (void)row; return unit;
#endif
}

// ---------------- K0: precompute alpha = sqrt(log2e/2)/sigma ; WO -> bf16 ----
__global__ __launch_bounds__(256) void k0_alpha(
    const float* __restrict__ sQ, const float* __restrict__ sK, const float* __restrict__ sV,
    float* __restrict__ aQ, float* __restrict__ aK, float* __restrict__ aV)
{
  int i = blockIdx.x * 256 + threadIdx.x;
  if (i < PAR){
    const float c = 0.8493218002880191f; // sqrt(log2(e)/2)
    aQ[i] = c / sQ[i];
    aK[i] = c / sK[i];
    aV[i] = c / sV[i];
  }
}

__global__ __launch_bounds__(256) void k0_wo(const float* __restrict__ WO, unsigned short* __restrict__ WOb)
{
  int i = blockIdx.x * 256 + threadIdx.x;
  if (i < DMc * DMc) WOb[i] = f2bf(WO[i]);
}

// ---------------- K1: gaussian basis * P + gamma  (f32 out) ------------------
// grid (H, NBL/64, 3proj), block 256 (4 waves).
// wave w owns d in [16w,16w+16) -> params wave-uniform (s_load); lane = row.
__global__ __launch_bounds__(256) void k1_gauss(
    const float* __restrict__ P, const float* __restrict__ t,
    const float* __restrict__ mu0, const float* __restrict__ al0, const float* __restrict__ w0, const float* __restrict__ gm0,
    const float* __restrict__ mu1, const float* __restrict__ al1, const float* __restrict__ w1, const float* __restrict__ gm1,
    const float* __restrict__ mu2, const float* __restrict__ al2, const float* __restrict__ w2, const float* __restrict__ gm2,
    float* __restrict__ o0, float* __restrict__ o1, float* __restrict__ o2)
{
  __shared__ float gbuf[64 * 65];
  const int h = blockIdx.x, tile = blockIdx.y, p = blockIdx.z;
  const int tid = threadIdx.x, wv = tid >> 6, lane = tid & 63;
  const int bl0 = tile * 64;

  const float* mu = (p == 0) ? mu0 : (p == 1) ? mu1 : mu2;
  const float* al = (p == 0) ? al0 : (p == 1) ? al1 : al2;
  const float* wp = (p == 0) ? w0  : (p == 1) ? w1  : w2;
  const float* gm = (p == 0) ? gm0 : (p == 1) ? gm1 : gm2;
  float*       op = (p == 0) ? o0  : (p == 1) ? o1  : o2;

  float tv[8];
  {
    const float4 t0 = *(const float4*)&t[(size_t)(bl0 + lane) * 8];
    const float4 t1 = *(const float4*)&t[(size_t)(bl0 + lane) * 8 + 4];
    tv[0] = t0.x; tv[1] = t0.y; tv[2] = t0.z; tv[3] = t0.w;
    tv[4] = t1.x; tv[5] = t1.y; tv[6] = t1.z; tv[7] = t1.w;
  }

  #pragma unroll 2
  for (int dd = 0; dd < 16; ++dd){
    const int d = wv * 16 + dd;
    const int base = (h * 64 + d) * 64;   // 64 (td,k) terms, wave-uniform
    float g0 = 0.f, g1 = 0.f, g2 = 0.f, g3 = 0.f;
    #pragma unroll
    for (int td = 0; td < 8; ++td){
      const float tval = tv[td];
      #pragma unroll
      for (int k = 0; k < 8; ++k){
        const int idx = base + td * 8 + k;
        const float u = (tval - mu[idx]) * al[idx];   // 2^(-u^2) == exp(-(t-mu)^2/(2s^2))
        const float e = exp2f(-u * u);
        if ((k & 3) == 0)      g0 = fmaf(wp[idx], e, g0);
        else if ((k & 3) == 1) g1 = fmaf(wp[idx], e, g1);
        else if ((k & 3) == 2) g2 = fmaf(wp[idx], e, g2);
        else                   g3 = fmaf(wp[idx], e, g3);
      }
    }
    gbuf[d * 65 + lane] = (g0 + g1) + (g2 + g3);
  }
  __syncthreads();

  { // transposed write phase: lanes = d (coalesced P read + output write)
    const int dl = tid & 63, rq = tid >> 6;
    const float gam = gm[h * 64 + dl];
    #pragma unroll 4
    for (int rr = 0; rr < 16; ++rr){
      const int r = rq * 16 + rr;
      const float g  = gbuf[dl * 65 + r];
      const float ph = P[(size_t)(bl0 + r) * DMc + h * 64 + dl];
      op[(size_t)(bl0 + r) * DMc + h * 64 + dl] = fmaf(g, ph, gam);
    }
  }
}

// ---------------- K2: per-head projection (f32 vector GEMM, 64x64 W) ---------
// grid (H, NBL/64), block 256.  PROJ 0=Q (f16 split, scaled log2e/8), 1=K (f16 split), 2=V (bf16 transposed)
template<int PROJ>
__global__ __launch_bounds__(256) void k2_proj(
    const float* __restrict__ Xg, const float* __restrict__ W,
    _Float16* __restrict__ Ohi, _Float16* __restrict__ Olo,
    unsigned short* __restrict__ Obf)
{
  __shared__ __align__(16) float Al[64 * 64];
  __shared__ __align__(16) float Wl[64 * 64];
  const int h = blockIdx.x, tile = blockIdx.y, tid = threadIdx.x;
  const int bl0 = tile * 64;

  for (int i = tid; i < 1024; i += 256){        // A tile: 64 rows x 64 d (f32)
    const int row = i >> 4, c4 = i & 15;
    *(float4*)&Al[row * 64 + c4 * 4] =
        *(const float4*)&Xg[(size_t)(bl0 + row) * DMc + h * 64 + c4 * 4];
  }
  for (int i = tid; i < 1024; i += 256){        // W[h]: 64 d x 64 f (f32)
    const int row = i >> 4, c4 = i & 15;
    *(float4*)&Wl[row * 64 + c4 * 4] =
        *(const float4*)&W[((size_t)h * 64 + row) * 64 + c4 * 4];
  }
  __syncthreads();

  const int f = tid & 63, q = tid >> 6;
  for (int r = q * 16; r < q * 16 + 16; ++r){
    float acc = 0.f;
    #pragma unroll 8
    for (int d = 0; d < 64; ++d) acc = fmaf(Al[r * 64 + d], Wl[d * 64 + f], acc);

    const int m = bl0 + r;             // flat (b,l)
    const int b = m >> 10, l = m & 1023;
    if constexpr (PROJ == 0){
      acc *= 0.18033688011112042f;     // log2(e) / sqrt(D), folds softmax scale+base-2
      const _Float16 hi = (_Float16)acc;
      const _Float16 lo = (_Float16)(acc - (float)hi);
      const size_t o = (((size_t)b * Hc + h) * Lc + l) * 64 + f;
      Ohi[o] = hi; Olo[o] = lo;
    } else if constexpr (PROJ == 1){
      const _Float16 hi = (_Float16)acc;
      const _Float16 lo = (_Float16)(acc - (float)hi);
      const size_t o = (((size_t)b * Hc + h) * Lc + l) * 64 + (swz(l, f >> 3) << 3) + (f & 7);
      Ohi[o] = hi; Olo[o] = lo;
    } else {
      const int m0v = l & ~63, ml = l & 63;   // V transposed: [b][h][f][m]
      const size_t o = (((size_t)b * Hc + h) * 64 + f) * Lc + m0v + (swz(f, ml >> 3) << 3) + (ml & 7);
      Obf[o] = f2bf(acc);
    }
  }
}

// ---------------- K3: flash attention, f16-split QK^T + bf16 PV --------------
// grid (B*H, L/64), block 256 (4 waves, each owns 16 q-rows).
__global__ __launch_bounds__(256) void k3_attn(
    const _Float16* __restrict__ Qhi, const _Float16* __restrict__ Qlo,
    const _Float16* __restrict__ Khi, const _Float16* __restrict__ Klo,
    const unsigned short* __restrict__ Vt,
    unsigned short* __restrict__ AO)
{
  __shared__ __align__(16) _Float16 KhiL[64 * 64];
  __shared__ __align__(16) _Float16 KloL[64 * 64];
  __shared__ __align__(16) unsigned short VL[64 * 64];   // [f][m]
  __shared__ __align__(16) unsigned short PL[4][16 * 64];
  const int bh = blockIdx.x, qt = blockIdx.y;
  const int tid = threadIdx.x, wv = tid >> 6, lane = tid & 63;
  const int lrow = lane & 15, lgrp = lane >> 4;
  const size_t bhL = (size_t)bh * Lc;

  f16x8 qh[2], ql[2];
  {
    const int qrow = qt * 64 + wv * 16 + lrow;
    const _Float16* q1 = &Qhi[(bhL + qrow) * 64 + lgrp * 8];
    const _Float16* q2 = &Qlo[(bhL + qrow) * 64 + lgrp * 8];
    qh[0] = *(const f16x8*)q1; qh[1] = *(const f16x8*)(q1 + 32);
    ql[0] = *(const f16x8*)q2; ql[1] = *(const f16x8*)(q2 + 32);
  }

  f32x4 o[4] = {};
  float mrun[4], lrun[4];
  #pragma unroll
  for (int r = 0; r < 4; ++r){ mrun[r] = -1e30f; lrun[r] = 0.f; }

  for (int kt = 0; kt < 16; ++kt){
    __syncthreads();
    { // stage K hi/lo (contiguous 8KB) + V tile rows (reg-staged)
      const char* ks_ = (const char*)(Khi + (bhL + kt * 64) * 64);
      const char* ls_ = (const char*)(Klo + (bhL + kt * 64) * 64);
      const char* vs_ = (const char*)(Vt + (size_t)bh * 64 * Lc + kt * 64);
      const int i0 = tid, i1 = tid + 256;
      f16x8 a0 = *(const f16x8*)(ks_ + i0 * 16);
      f16x8 a1 = *(const f16x8*)(ks_ + i1 * 16);
      f16x8 b0 = *(const f16x8*)(ls_ + i0 * 16);
      f16x8 b1 = *(const f16x8*)(ls_ + i1 * 16);
      s16x8 c0 = *(const s16x8*)(vs_ + (i0 >> 3) * 2048 + (i0 & 7) * 16);
      s16x8 c1 = *(const s16x8*)(vs_ + (i1 >> 3) * 2048 + (i1 & 7) * 16);
      *(f16x8*)((char*)KhiL + i0 * 16) = a0;
      *(f16x8*)((char*)KhiL + i1 * 16) = a1;
      *(f16x8*)((char*)KloL + i0 * 16) = b0;
      *(f16x8*)((char*)KloL + i1 * 16) = b1;
      *(s16x8*)((char*)VL + i0 * 16) = c0;
      *(s16x8*)((char*)VL + i1 * 16) = c1;
    }
    __syncthreads();

    // S = Q.K^T in exp2 domain (3-pass f16 split: hh + lh + hl)
    f32x4 s[4] = {};
    #pragma unroll
    for (int tt = 0; tt < 4; ++tt){
      #pragma unroll
      for (int ks = 0; ks < 2; ++ks){
        const int m = tt * 16 + lrow;
        const int off = m * 128 + swz(m, ks * 4 + lgrp) * 16;
        f16x8 kh_ = *(const f16x8*)((const char*)KhiL + off);
        f16x8 kl_ = *(const f16x8*)((const char*)KloL + off);
        s[tt] = __builtin_amdgcn_mfma_f32_16x16x32_f16(qh[ks], kh_, s[tt], 0, 0, 0);
        s[tt] = __builtin_amdgcn_mfma_f32_16x16x32_f16(ql[ks], kh_, s[tt], 0, 0, 0);
        s[tt] = __builtin_amdgcn_mfma_f32_16x16x32_f16(qh[ks], kl_, s[tt], 0, 0, 0);
      }
    }

    // online softmax (rows l = lgrp*4 + r ; m spread across 16 lanes x 4 tiles)
    float sc[4];
    #pragma unroll
    for (int r = 0; r < 4; ++r){
      float v = fmaxf(fmaxf(s[0][r], s[1][r]), fmaxf(s[2][r], s[3][r]));
      v = fmaxf(v, __shfl_xor(v, 1));
      v = fmaxf(v, __shfl_xor(v, 2));
      v = fmaxf(v, __shfl_xor(v, 4));
      v = fmaxf(v, __shfl_xor(v, 8));
      const float mn = fmaxf(mrun[r], v);
      sc[r] = exp2f(mrun[r] - mn);
      mrun[r] = mn;
    }
    float rs[4] = {0.f, 0.f, 0.f, 0.f};
    unsigned short pb[4][4];
    #pragma unroll
    for (int tt = 0; tt < 4; ++tt){
      #pragma unroll
      for (int r = 0; r < 4; ++r){
        const float p = exp2f(s[tt][r] - mrun[r]);
        rs[r] += p;
        pb[tt][r] = f2bf(p);
      }
    }
    #pragma unroll
    for (int r = 0; r < 4; ++r){
      float v = rs[r];
      v += __shfl_xor(v, 1); v += __shfl_xor(v, 2); v += __shfl_xor(v, 4); v += __shfl_xor(v, 8);
      lrun[r] = lrun[r] * sc[r] + v;
      o[0][r] *= sc[r]; o[1][r] *= sc[r]; o[2][r] *= sc[r]; o[3][r] *= sc[r];
    }

    // P -> per-wave LDS (bf16), then PV MFMA (no barrier needed: wave-private)
    unsigned short* pw = (unsigned short*)PL[wv];
    #pragma unroll
    for (int tt = 0; tt < 4; ++tt){
      const int m = tt * 16 + lrow;
      #pragma unroll
      for (int r = 0; r < 4; ++r){
        const int l = lgrp * 4 + r;
        *(unsigned short*)((char*)pw + l * 128 + swz(l, m >> 3) * 16 + (m & 7) * 2) = pb[tt][r];
      }
    }
    #pragma unroll
    for (int ks = 0; ks < 2; ++ks){
      const int poff = lrow * 128 + swz(lrow, ks * 4 + lgrp) * 16;
      s16x8 pa = *(const s16x8*)((const char*)pw + poff);
      #pragma unroll
      for (int t2 = 0; t2 < 4; ++t2){
        const int f = t2 * 16 + lrow;
        const int voff = f * 128 + swz(f, ks * 4 + lgrp) * 16;
        s16x8 vb = *(const s16x8*)((const char*)VL + voff);
        o[t2] = __builtin_amdgcn_mfma_f32_16x16x32_bf16(pa, vb, o[t2], 0, 0, 0);
      }
    }
  }

  const int b = bh >> 4, hh = bh & 15;
  #pragma unroll
  for (int r = 0; r < 4; ++r){
    const float inv = 1.0f / lrun[r];
    const int l = qt * 64 + wv * 16 + lgrp * 4 + r;
    #pragma unroll
    for (int t2 = 0; t2 < 4; ++t2){
      const int f = t2 * 16 + lrow;
      AO[((size_t)(b * Lc + l)) * DMc + hh * 64 + f] = f2bf(o[t2][r] * inv);
    }
  }
}

// ---------------- K4: out = attn @ W_O^T + b  (bf16 MFMA GEMM, f32 out) ------
// grid (NBL/128, DM/128), block 256 (2x2 waves, each 64x64).
__global__ __launch_bounds__(256) void k4_out(
    const unsigned short* __restrict__ A, const unsigned short* __restrict__ Bw,
    const float* __restrict__ bias, float* __restrict__ out)
{
  __shared__ __align__(16) unsigned short Asl[128 * 64];
  __shared__ __align__(16) unsigned short Bsl[128 * 64];
  const int mt = blockIdx.x, nt = blockIdx.y;
  const int tid = threadIdx.x, wv = tid >> 6, lane = tid & 63;
  const int wr = wv >> 1, wc = wv & 1, lrow = lane & 15, lgrp = lane >> 4;
  f32x4 acc[4][4] = {};
  const char* abase = (const char*)A  + (size_t)mt * 128 * 2048;
  const char* bbase = (const char*)Bw + (size_t)nt * 128 * 2048;

  for (int kt = 0; kt < 16; ++kt){
    __syncthreads();
    #pragma unroll
    for (int q = 0; q < 4; ++q){
      const int i = q * 256 + tid, row = i >> 3, u = i & 7;
      s16x8 av = *(const s16x8*)(abase + (size_t)row * 2048 + kt * 128 + u * 16);
      s16x8 bv = *(const s16x8*)(bbase + (size_t)row * 2048 + kt * 128 + u * 16);
      *(s16x8*)((char*)Asl + row * 128 + swz(row, u) * 16) = av;
      *(s16x8*)((char*)Bsl + row * 128 + swz(row, u) * 16) = bv;
    }
    __syncthreads();
    #pragma unroll
    for (int ks = 0; ks < 2; ++ks){
      s16x8 af[4], bf[4];
      #pragma unroll
      for (int i4 = 0; i4 < 4; ++i4){
        const int row = wr * 64 + i4 * 16 + lrow;
        af[i4] = *(const s16x8*)((const char*)Asl + row * 128 + swz(row, ks * 4 + lgrp) * 16);
        const int col = wc * 64 + i4 * 16 + lrow;
        bf[i4] = *(const s16x8*)((const char*)Bsl + col * 128 + swz(col, ks * 4 + lgrp) * 16);
      }
      #pragma unroll
      for (int i4 = 0; i4 < 4; ++i4)
        #pragma unroll
        for (int j4 = 0; j4 < 4; ++j4)
          acc[i4][j4] = __builtin_amdgcn_mfma_f32_16x16x32_bf16(af[i4], bf[j4], acc[i4][j4], 0, 0, 0);
    }
  }
  #pragma unroll
  for (int i4 = 0; i4 < 4; ++i4)
    #pragma unroll
    for (int j4 = 0; j4 < 4; ++j4){
      const int col = nt * 128 + wc * 64 + j4 * 16 + lrow;
      const float bb = bias[col];
      #pragma unroll
      for (int r = 0; r < 4; ++r){
        const int row = mt * 128 + wr * 64 + i4 * 16 + lgrp * 4 + r;
        out[(size_t)row * DMc + col] = acc[i4][j4][r] + bb;
      }
    }
}

// ---------------- launch -----------------------------------------------------
extern "C" void kernel_launch(void* const* d_in, const int* in_sizes, int n_in,
                              void* d_out, int out_size, void* d_ws, size_t ws_size,
                              hipStream_t stream)
{
  const float* P   = (const float*)d_in[0];
  const float* t   = (const float*)d_in[1];
  const float* muQ = (const float*)d_in[2];
  const float* sgQ = (const float*)d_in[3];
  const float* wQ  = (const float*)d_in[4];
  const float* gQ  = (const float*)d_in[5];
  const float* WQ  = (const float*)d_in[6];
  const float* muK = (const float*)d_in[7];
  const float* sgK = (const float*)d_in[8];
  const float* wK  = (const float*)d_in[9];
  const float* gK  = (const float*)d_in[10];
  const float* WK  = (const float*)d_in[11];
  const float* muV = (const float*)d_in[12];
  const float* sgV = (const float*)d_in[13];
  const float* wV  = (const float*)d_in[14];
  const float* gV  = (const float*)d_in[15];
  const float* WV  = (const float*)d_in[16];
  const float* WO  = (const float*)d_in[17];
  const float* WOb = (const float*)d_in[18];

  char* w = (char*)d_ws;
  auto take = [&](size_t bytes) -> char* {
    char* p = w; w += (bytes + 255) & ~(size_t)255; return p;
  };
  float* aQ = (float*)take((size_t)PAR * 4);
  float* aK = (float*)take((size_t)PAR * 4);
  float* aV = (float*)take((size_t)PAR * 4);
  float* Qg = (float*)take((size_t)NBL * DMc * 4);
  float* Kg = (float*)take((size_t)NBL * DMc * 4);
  float* Vg = (float*)take((size_t)NBL * DMc * 4);
  _Float16* Qhi = (_Float16*)take((size_t)NBL * DMc * 2);
  _Float16* Qlo = (_Float16*)take((size_t)NBL * DMc * 2);
  _Float16* Khi = (_Float16*)take((size_t)NBL * DMc * 2);
  _Float16* Klo = (_Float16*)take((size_t)NBL * DMc * 2);
  unsigned short* Vt    = (unsigned short*)take((size_t)NBL * DMc * 2);
  unsigned short* AO    = (unsigned short*)take((size_t)NBL * DMc * 2);
  unsigned short* WOb16 = (unsigned short*)take((size_t)DMc * DMc * 2);
  if ((size_t)(w - (char*)d_ws) > ws_size) return;  // insufficient scratch: bail

  k0_alpha<<<PAR / 256, 256, 0, stream>>>(sgQ, sgK, sgV, aQ, aK, aV);
  k0_wo<<<DMc * DMc / 256, 256, 0, stream>>>(WO, WOb16);
  k1_gauss<<<dim3(Hc, NBL / 64, 3), 256, 0, stream>>>(P, t,
      muQ, aQ, wQ, gQ,  muK, aK, wK, gK,  muV, aV, wV, gV,  Qg, Kg, Vg);
  k2_proj<0><<<dim3(Hc, NBL / 64), 256, 0, stream>>>(Qg, WQ, Qhi, Qlo, nullptr);
  k2_proj<1><<<dim3(Hc, NBL / 64), 256, 0, stream>>>(Kg, WK, Khi, Klo, nullptr);
  k2_proj<2><<<dim3(Hc, NBL / 64), 256, 0, stream>>>(Vg, WV, nullptr, nullptr, Vt);
  k3_attn<<<dim3(Bc * Hc, Lc / 64), 256, 0, stream>>>(Qhi, Qlo, Khi, Klo, Vt, AO);
  k4_out<<<dim3(NBL / 128, DMc / 128), 256, 0, stream>>>(AO, WOb16, WOb, (float*)d_out);
}

// Round 3
// 354.440 us; speedup vs baseline: 3.2275x; 1.6120x over previous
//
#include <hip/hip_runtime.h>
#include <cstdint>

#define DEVI __device__ __forceinline__

constexpr int Bc = 4, Lc = 1024, DMc = 1024, Hc = 16, TDc = 8, Kc = 8, Dc = 64;
constexpr int NBL = Bc * Lc;               // 4096
constexpr int PAR = Hc * Dc * TDc * Kc;    // 65536 per param array

using f16x8 = __attribute__((ext_vector_type(8))) _Float16;
using s16x8 = __attribute__((ext_vector_type(8))) short;
using f32x4 = __attribute__((ext_vector_type(4))) float;

DEVI unsigned short f2bf(float x){
  union { float f; unsigned u; } v; v.f = x;
  return (unsigned short)((v.u + 0x7fffu + ((v.u >> 16) & 1u)) >> 16);
}

// LDS swizzle hook — identity (correctness baseline); flip to 1 later.
#define SWZ_ON 0
DEVI int swz(int row, int unit){
#if SWZ_ON
  return unit ^ (row & 7);
#else
  (void)row; return unit;
#endif
}

// ---------------- K0: precompute alpha = sqrt(log2e/2)/sigma ; WO -> bf16 ----
__global__ __launch_bounds__(256) void k0_alpha(
    const float* __restrict__ sQ, const float* __restrict__ sK, const float* __restrict__ sV,
    float* __restrict__ aQ, float* __restrict__ aK, float* __restrict__ aV)
{
  int i = blockIdx.x * 256 + threadIdx.x;
  if (i < PAR){
    const float c = 0.8493218002880191f; // sqrt(log2(e)/2)
    aQ[i] = c / sQ[i];
    aK[i] = c / sK[i];
    aV[i] = c / sV[i];
  }
}

__global__ __launch_bounds__(256) void k0_wo(const float* __restrict__ WO, unsigned short* __restrict__ WOb)
{
  int i = blockIdx.x * 256 + threadIdx.x;
  if (i < DMc * DMc) WOb[i] = f2bf(WO[i]);
}

// ---------------- K1: gaussian basis * P + gamma  (f32 out) ------------------
// grid (H, NBL/64, 3proj), block 256 (4 waves).
// wave w owns d in [16w,16w+16); readfirstlane forces uniformity proof so
// mu/al/w reads become batched s_load (off the VALU pipe).
__global__ __launch_bounds__(256) void k1_gauss(
    const float* __restrict__ P, const float* __restrict__ t,
    const float* __restrict__ mu0, const float* __restrict__ al0, const float* __restrict__ w0, const float* __restrict__ gm0,
    const float* __restrict__ mu1, const float* __restrict__ al1, const float* __restrict__ w1, const float* __restrict__ gm1,
    const float* __restrict__ mu2, const float* __restrict__ al2, const float* __restrict__ w2, const float* __restrict__ gm2,
    float* __restrict__ o0, float* __restrict__ o1, float* __restrict__ o2)
{
  __shared__ float gbuf[64 * 65];
  const int h = blockIdx.x, tile = blockIdx.y, p = blockIdx.z;
  const int tid = threadIdx.x, lane = tid & 63;
  const int wv = __builtin_amdgcn_readfirstlane(tid >> 6);   // wave-uniform in SGPR
  const int bl0 = tile * 64;

  const float* mu = (p == 0) ? mu0 : (p == 1) ? mu1 : mu2;
  const float* al = (p == 0) ? al0 : (p == 1) ? al1 : al2;
  const float* wp = (p == 0) ? w0  : (p == 1) ? w1  : w2;
  const float* gm = (p == 0) ? gm0 : (p == 1) ? gm1 : gm2;
  float*       op = (p == 0) ? o0  : (p == 1) ? o1  : o2;

  float tv[8];
  {
    const float4 t0 = *(const float4*)&t[(size_t)(bl0 + lane) * 8];
    const float4 t1 = *(const float4*)&t[(size_t)(bl0 + lane) * 8 + 4];
    tv[0] = t0.x; tv[1] = t0.y; tv[2] = t0.z; tv[3] = t0.w;
    tv[4] = t1.x; tv[5] = t1.y; tv[6] = t1.z; tv[7] = t1.w;
  }

  #pragma unroll 2
  for (int dd = 0; dd < 16; ++dd){
    const int d = wv * 16 + dd;
    const int base = (h * 64 + d) * 64;   // 64 (td,k) terms, wave-uniform -> s_load
    float g0 = 0.f, g1 = 0.f, g2 = 0.f, g3 = 0.f;
    #pragma unroll
    for (int td = 0; td < 8; ++td){
      const float tval = tv[td];
      #pragma unroll
      for (int k = 0; k < 8; ++k){
        const int idx = base + td * 8 + k;
        const float u = (tval - mu[idx]) * al[idx];   // 2^(-u^2) == exp(-(t-mu)^2/(2s^2))
        const float e = __builtin_amdgcn_exp2f(-(u * u));
        if ((k & 3) == 0)      g0 = fmaf(wp[idx], e, g0);
        else if ((k & 3) == 1) g1 = fmaf(wp[idx], e, g1);
        else if ((k & 3) == 2) g2 = fmaf(wp[idx], e, g2);
        else                   g3 = fmaf(wp[idx], e, g3);
      }
    }
    gbuf[d * 65 + lane] = (g0 + g1) + (g2 + g3);
  }
  __syncthreads();

  { // transposed write phase: lanes = d (coalesced P read + output write)
    const int dl = tid & 63, rq = tid >> 6;
    const float gam = gm[h * 64 + dl];
    #pragma unroll 4
    for (int rr = 0; rr < 16; ++rr){
      const int r = rq * 16 + rr;
      const float g  = gbuf[dl * 65 + r];
      const float ph = P[(size_t)(bl0 + r) * DMc + h * 64 + dl];
      op[(size_t)(bl0 + r) * DMc + h * 64 + dl] = fmaf(g, ph, gam);
    }
  }
}

// ---------------- K2: per-head projection (f32, W-col in VGPRs, A via s_load) -
// grid (H, NBL/64), block 256.  PROJ 0=Q (f16 split, scaled log2e/8), 1=K (f16 split), 2=V (bf16 transposed)
template<int PROJ>
__global__ __launch_bounds__(256) void k2_proj(
    const float* __restrict__ Xg, const float* __restrict__ W,
    _Float16* __restrict__ Ohi, _Float16* __restrict__ Olo,
    unsigned short* __restrict__ Obf)
{
  __shared__ __align__(16) float Wl[64 * 64];
  const int h = blockIdx.x, tile = blockIdx.y, tid = threadIdx.x;
  const int bl0 = tile * 64;
  const int f = tid & 63;
  const int q = __builtin_amdgcn_readfirstlane(tid >> 6);  // wave-uniform row group

  for (int i = tid; i < 1024; i += 256){        // W[h]: 64 d x 64 f (f32)
    const int row = i >> 4, c4 = i & 15;
    *(float4*)&Wl[row * 64 + c4 * 4] =
        *(const float4*)&W[((size_t)h * 64 + row) * 64 + c4 * 4];
  }
  __syncthreads();

  float wcol[64];                               // this lane's W column
  #pragma unroll
  for (int d = 0; d < 64; ++d) wcol[d] = Wl[d * 64 + f];

  #pragma unroll 1
  for (int r = 0; r < 16; ++r){
    const int m = bl0 + q * 16 + r;             // flat (b,l), wave-uniform
    const float* ar = &Xg[(size_t)m * DMc + h * 64];   // uniform addr -> s_load
    float a0 = 0.f, a1 = 0.f, a2 = 0.f, a3 = 0.f;
    #pragma unroll
    for (int d = 0; d < 64; d += 4){
      a0 = fmaf(ar[d + 0], wcol[d + 0], a0);
      a1 = fmaf(ar[d + 1], wcol[d + 1], a1);
      a2 = fmaf(ar[d + 2], wcol[d + 2], a2);
      a3 = fmaf(ar[d + 3], wcol[d + 3], a3);
    }
    float acc = (a0 + a1) + (a2 + a3);

    const int b = m >> 10, l = m & 1023;
    if constexpr (PROJ == 0){
      acc *= 0.18033688011112042f;     // log2(e) / sqrt(D), folds softmax scale+base-2
      const _Float16 hi = (_Float16)acc;
      const _Float16 lo = (_Float16)(acc - (float)hi);
      const size_t o = (((size_t)b * Hc + h) * Lc + l) * 64 + f;
      Ohi[o] = hi; Olo[o] = lo;
    } else if constexpr (PROJ == 1){
      const _Float16 hi = (_Float16)acc;
      const _Float16 lo = (_Float16)(acc - (float)hi);
      const size_t o = (((size_t)b * Hc + h) * Lc + l) * 64 + (swz(l, f >> 3) << 3) + (f & 7);
      Ohi[o] = hi; Olo[o] = lo;
    } else {
      const int m0v = l & ~63, ml = l & 63;   // V transposed: [b][h][f][m]
      const size_t o = (((size_t)b * Hc + h) * 64 + f) * Lc + m0v + (swz(f, ml >> 3) << 3) + (ml & 7);
      Obf[o] = f2bf(acc);
    }
  }
}

// ---------------- K3: flash attention, f16-split QK^T + bf16 PV --------------
// grid (B*H, L/64), block 256 (4 waves, each owns 16 q-rows).
__global__ __launch_bounds__(256) void k3_attn(
    const _Float16* __restrict__ Qhi, const _Float16* __restrict__ Qlo,
    const _Float16* __restrict__ Khi, const _Float16* __restrict__ Klo,
    const unsigned short* __restrict__ Vt,
    unsigned short* __restrict__ AO)
{
  __shared__ __align__(16) _Float16 KhiL[64 * 64];
  __shared__ __align__(16) _Float16 KloL[64 * 64];
  __shared__ __align__(16) unsigned short VL[64 * 64];   // [f][m]
  __shared__ __align__(16) unsigned short PL[4][16 * 64];
  const int bh = blockIdx.x, qt = blockIdx.y;
  const int tid = threadIdx.x, wv = tid >> 6, lane = tid & 63;
  const int lrow = lane & 15, lgrp = lane >> 4;
  const size_t bhL = (size_t)bh * Lc;

  f16x8 qh[2], ql[2];
  {
    const int qrow = qt * 64 + wv * 16 + lrow;
    const _Float16* q1 = &Qhi[(bhL + qrow) * 64 + lgrp * 8];
    const _Float16* q2 = &Qlo[(bhL + qrow) * 64 + lgrp * 8];
    qh[0] = *(const f16x8*)q1; qh[1] = *(const f16x8*)(q1 + 32);
    ql[0] = *(const f16x8*)q2; ql[1] = *(const f16x8*)(q2 + 32);
  }

  f32x4 o[4] = {};
  float mrun[4], lrun[4];
  #pragma unroll
  for (int r = 0; r < 4; ++r){ mrun[r] = -1e30f; lrun[r] = 0.f; }

  for (int kt = 0; kt < 16; ++kt){
    __syncthreads();
    { // stage K hi/lo (contiguous 8KB) + V tile rows (reg-staged)
      const char* ks_ = (const char*)(Khi + (bhL + kt * 64) * 64);
      const char* ls_ = (const char*)(Klo + (bhL + kt * 64) * 64);
      const char* vs_ = (const char*)(Vt + (size_t)bh * 64 * Lc + kt * 64);
      const int i0 = tid, i1 = tid + 256;
      f16x8 a0 = *(const f16x8*)(ks_ + i0 * 16);
      f16x8 a1 = *(const f16x8*)(ks_ + i1 * 16);
      f16x8 b0 = *(const f16x8*)(ls_ + i0 * 16);
      f16x8 b1 = *(const f16x8*)(ls_ + i1 * 16);
      s16x8 c0 = *(const s16x8*)(vs_ + (i0 >> 3) * 2048 + (i0 & 7) * 16);
      s16x8 c1 = *(const s16x8*)(vs_ + (i1 >> 3) * 2048 + (i1 & 7) * 16);
      *(f16x8*)((char*)KhiL + i0 * 16) = a0;
      *(f16x8*)((char*)KhiL + i1 * 16) = a1;
      *(f16x8*)((char*)KloL + i0 * 16) = b0;
      *(f16x8*)((char*)KloL + i1 * 16) = b1;
      *(s16x8*)((char*)VL + i0 * 16) = c0;
      *(s16x8*)((char*)VL + i1 * 16) = c1;
    }
    __syncthreads();

    // S = Q.K^T in exp2 domain (3-pass f16 split: hh + lh + hl)
    f32x4 s[4] = {};
    #pragma unroll
    for (int tt = 0; tt < 4; ++tt){
      #pragma unroll
      for (int ks = 0; ks < 2; ++ks){
        const int m = tt * 16 + lrow;
        const int off = m * 128 + swz(m, ks * 4 + lgrp) * 16;
        f16x8 kh_ = *(const f16x8*)((const char*)KhiL + off);
        f16x8 kl_ = *(const f16x8*)((const char*)KloL + off);
        s[tt] = __builtin_amdgcn_mfma_f32_16x16x32_f16(qh[ks], kh_, s[tt], 0, 0, 0);
        s[tt] = __builtin_amdgcn_mfma_f32_16x16x32_f16(ql[ks], kh_, s[tt], 0, 0, 0);
        s[tt] = __builtin_amdgcn_mfma_f32_16x16x32_f16(qh[ks], kl_, s[tt], 0, 0, 0);
      }
    }

    // online softmax (rows l = lgrp*4 + r ; m spread across 16 lanes x 4 tiles)
    float sc[4];
    #pragma unroll
    for (int r = 0; r < 4; ++r){
      float v = fmaxf(fmaxf(s[0][r], s[1][r]), fmaxf(s[2][r], s[3][r]));
      v = fmaxf(v, __shfl_xor(v, 1));
      v = fmaxf(v, __shfl_xor(v, 2));
      v = fmaxf(v, __shfl_xor(v, 4));
      v = fmaxf(v, __shfl_xor(v, 8));
      const float mn = fmaxf(mrun[r], v);
      sc[r] = exp2f(mrun[r] - mn);
      mrun[r] = mn;
    }
    float rs[4] = {0.f, 0.f, 0.f, 0.f};
    unsigned short pb[4][4];
    #pragma unroll
    for (int tt = 0; tt < 4; ++tt){
      #pragma unroll
      for (int r = 0; r < 4; ++r){
        const float p = exp2f(s[tt][r] - mrun[r]);
        rs[r] += p;
        pb[tt][r] = f2bf(p);
      }
    }
    #pragma unroll
    for (int r = 0; r < 4; ++r){
      float v = rs[r];
      v += __shfl_xor(v, 1); v += __shfl_xor(v, 2); v += __shfl_xor(v, 4); v += __shfl_xor(v, 8);
      lrun[r] = lrun[r] * sc[r] + v;
      o[0][r] *= sc[r]; o[1][r] *= sc[r]; o[2][r] *= sc[r]; o[3][r] *= sc[r];
    }

    // P -> per-wave LDS (bf16), then PV MFMA (no barrier needed: wave-private)
    unsigned short* pw = (unsigned short*)PL[wv];
    #pragma unroll
    for (int tt = 0; tt < 4; ++tt){
      const int m = tt * 16 + lrow;
      #pragma unroll
      for (int r = 0; r < 4; ++r){
        const int l = lgrp * 4 + r;
        *(unsigned short*)((char*)pw + l * 128 + swz(l, m >> 3) * 16 + (m & 7) * 2) = pb[tt][r];
      }
    }
    #pragma unroll
    for (int ks = 0; ks < 2; ++ks){
      const int poff = lrow * 128 + swz(lrow, ks * 4 + lgrp) * 16;
      s16x8 pa = *(const s16x8*)((const char*)pw + poff);
      #pragma unroll
      for (int t2 = 0; t2 < 4; ++t2){
        const int f = t2 * 16 + lrow;
        const int voff = f * 128 + swz(f, ks * 4 + lgrp) * 16;
        s16x8 vb = *(const s16x8*)((const char*)VL + voff);
        o[t2] = __builtin_amdgcn_mfma_f32_16x16x32_bf16(pa, vb, o[t2], 0, 0, 0);
      }
    }
  }

  const int b = bh >> 4, hh = bh & 15;
  #pragma unroll
  for (int r = 0; r < 4; ++r){
    const float inv = 1.0f / lrun[r];
    const int l = qt * 64 + wv * 16 + lgrp * 4 + r;
    #pragma unroll
    for (int t2 = 0; t2 < 4; ++t2){
      const int f = t2 * 16 + lrow;
      AO[((size_t)(b * Lc + l)) * DMc + hh * 64 + f] = f2bf(o[t2][r] * inv);
    }
  }
}

// ---------------- K4: out = attn @ W_O^T + b  (bf16 MFMA GEMM, f32 out) ------
// grid (NBL/128, DM/128), block 256 (2x2 waves, each 64x64).
__global__ __launch_bounds__(256) void k4_out(
    const unsigned short* __restrict__ A, const unsigned short* __restrict__ Bw,
    const float* __restrict__ bias, float* __restrict__ out)
{
  __shared__ __align__(16) unsigned short Asl[128 * 64];
  __shared__ __align__(16) unsigned short Bsl[128 * 64];
  const int mt = blockIdx.x, nt = blockIdx.y;
  const int tid = threadIdx.x, wv = tid >> 6, lane = tid & 63;
  const int wr = wv >> 1, wc = wv & 1, lrow = lane & 15, lgrp = lane >> 4;
  f32x4 acc[4][4] = {};
  const char* abase = (const char*)A  + (size_t)mt * 128 * 2048;
  const char* bbase = (const char*)Bw + (size_t)nt * 128 * 2048;

  for (int kt = 0; kt < 16; ++kt){
    __syncthreads();
    #pragma unroll
    for (int q = 0; q < 4; ++q){
      const int i = q * 256 + tid, row = i >> 3, u = i & 7;
      s16x8 av = *(const s16x8*)(abase + (size_t)row * 2048 + kt * 128 + u * 16);
      s16x8 bv = *(const s16x8*)(bbase + (size_t)row * 2048 + kt * 128 + u * 16);
      *(s16x8*)((char*)Asl + row * 128 + swz(row, u) * 16) = av;
      *(s16x8*)((char*)Bsl + row * 128 + swz(row, u) * 16) = bv;
    }
    __syncthreads();
    #pragma unroll
    for (int ks = 0; ks < 2; ++ks){
      s16x8 af[4], bf[4];
      #pragma unroll
      for (int i4 = 0; i4 < 4; ++i4){
        const int row = wr * 64 + i4 * 16 + lrow;
        af[i4] = *(const s16x8*)((const char*)Asl + row * 128 + swz(row, ks * 4 + lgrp) * 16);
        const int col = wc * 64 + i4 * 16 + lrow;
        bf[i4] = *(const s16x8*)((const char*)Bsl + col * 128 + swz(col, ks * 4 + lgrp) * 16);
      }
      #pragma unroll
      for (int i4 = 0; i4 < 4; ++i4)
        #pragma unroll
        for (int j4 = 0; j4 < 4; ++j4)
          acc[i4][j4] = __builtin_amdgcn_mfma_f32_16x16x32_bf16(af[i4], bf[j4], acc[i4][j4], 0, 0, 0);
    }
  }
  #pragma unroll
  for (int i4 = 0; i4 < 4; ++i4)
    #pragma unroll
    for (int j4 = 0; j4 < 4; ++j4){
      const int col = nt * 128 + wc * 64 + j4 * 16 + lrow;
      const float bb = bias[col];
      #pragma unroll
      for (int r = 0; r < 4; ++r){
        const int row = mt * 128 + wr * 64 + i4 * 16 + lgrp * 4 + r;
        out[(size_t)row * DMc + col] = acc[i4][j4][r] + bb;
      }
    }
}

// ---------------- launch -----------------------------------------------------
extern "C" void kernel_launch(void* const* d_in, const int* in_sizes, int n_in,
                              void* d_out, int out_size, void* d_ws, size_t ws_size,
                              hipStream_t stream)
{
  const float* P   = (const float*)d_in[0];
  const float* t   = (const float*)d_in[1];
  const float* muQ = (const float*)d_in[2];
  const float* sgQ = (const float*)d_in[3];
  const float* wQ  = (const float*)d_in[4];
  const float* gQ  = (const float*)d_in[5];
  const float* WQ  = (const float*)d_in[6];
  const float* muK = (const float*)d_in[7];
  const float* sgK = (const float*)d_in[8];
  const float* wK  = (const float*)d_in[9];
  const float* gK  = (const float*)d_in[10];
  const float* WK  = (const float*)d_in[11];
  const float* muV = (const float*)d_in[12];
  const float* sgV = (const float*)d_in[13];
  const float* wV  = (const float*)d_in[14];
  const float* gV  = (const float*)d_in[15];
  const float* WV  = (const float*)d_in[16];
  const float* WO  = (const float*)d_in[17];
  const float* WOb = (const float*)d_in[18];

  char* w = (char*)d_ws;
  auto take = [&](size_t bytes) -> char* {
    char* p = w; w += (bytes + 255) & ~(size_t)255; return p;
  };
  float* aQ = (float*)take((size_t)PAR * 4);
  float* aK = (float*)take((size_t)PAR * 4);
  float* aV = (float*)take((size_t)PAR * 4);
  float* Qg = (float*)take((size_t)NBL * DMc * 4);
  float* Kg = (float*)take((size_t)NBL * DMc * 4);
  float* Vg = (float*)take((size_t)NBL * DMc * 4);
  _Float16* Qhi = (_Float16*)take((size_t)NBL * DMc * 2);
  _Float16* Qlo = (_Float16*)take((size_t)NBL * DMc * 2);
  _Float16* Khi = (_Float16*)take((size_t)NBL * DMc * 2);
  _Float16* Klo = (_Float16*)take((size_t)NBL * DMc * 2);
  unsigned short* Vt    = (unsigned short*)take((size_t)NBL * DMc * 2);
  unsigned short* AO    = (unsigned short*)take((size_t)NBL * DMc * 2);
  unsigned short* WOb16 = (unsigned short*)take((size_t)DMc * DMc * 2);
  if ((size_t)(w - (char*)d_ws) > ws_size) return;  // insufficient scratch: bail

  k0_alpha<<<PAR / 256, 256, 0, stream>>>(sgQ, sgK, sgV, aQ, aK, aV);
  k0_wo<<<DMc * DMc / 256, 256, 0, stream>>>(WO, WOb16);
  k1_gauss<<<dim3(Hc, NBL / 64, 3), 256, 0, stream>>>(P, t,
      muQ, aQ, wQ, gQ,  muK, aK, wK, gK,  muV, aV, wV, gV,  Qg, Kg, Vg);
  k2_proj<0><<<dim3(Hc, NBL / 64), 256, 0, stream>>>(Qg, WQ, Qhi, Qlo, nullptr);
  k2_proj<1><<<dim3(Hc, NBL / 64), 256, 0, stream>>>(Kg, WK, Khi, Klo, nullptr);
  k2_proj<2><<<dim3(Hc, NBL / 64), 256, 0, stream>>>(Vg, WV, nullptr, nullptr, Vt);
  k3_attn<<<dim3(Bc * Hc, Lc / 64), 256, 0, stream>>>(Qhi, Qlo, Khi, Klo, Vt, AO);
  k4_out<<<dim3(NBL / 128, DMc / 128), 256, 0, stream>>>(AO, WOb16, WOb, (float*)d_out);
}

// Round 4
// 349.568 us; speedup vs baseline: 3.2725x; 1.0139x over previous
//
#include <hip/hip_runtime.h>
#include <cstdint>

#define DEVI __device__ __forceinline__

constexpr int Bc = 4, Lc = 1024, DMc = 1024, Hc = 16, TDc = 8, Kc = 8, Dc = 64;
constexpr int NBL = Bc * Lc;               // 4096
constexpr int PAR = Hc * Dc * TDc * Kc;    // 65536 per param array

using f16x8 = __attribute__((ext_vector_type(8))) _Float16;
using s16x8 = __attribute__((ext_vector_type(8))) short;
using f32x4 = __attribute__((ext_vector_type(4))) float;

DEVI unsigned short f2bf(float x){
  union { float f; unsigned u; } v; v.f = x;
  return (unsigned short)((v.u + 0x7fffu + ((v.u >> 16) & 1u)) >> 16);
}

// LDS swizzle — ON this round (write/read pairs audited r0; k2 pre-swizzles K/V global layout).
#define SWZ_ON 1
DEVI int swz(int row, int unit){
#if SWZ_ON
  return unit ^ (row & 7);
#else
  (void)row; return unit;
#endif
}

// ---------------- K0: precompute alpha = sqrt(log2e/2)/sigma ; WO -> bf16 ----
__global__ __launch_bounds__(256) void k0_alpha(
    const float* __restrict__ sQ, const float* __restrict__ sK, const float* __restrict__ sV,
    float* __restrict__ aQ, float* __restrict__ aK, float* __restrict__ aV)
{
  int i = blockIdx.x * 256 + threadIdx.x;
  if (i < PAR){
    const float c = 0.8493218002880191f; // sqrt(log2(e)/2)
    aQ[i] = c / sQ[i];
    aK[i] = c / sK[i];
    aV[i] = c / sV[i];
  }
}

__global__ __launch_bounds__(256) void k0_wo(const float* __restrict__ WO, unsigned short* __restrict__ WOb)
{
  int i = blockIdx.x * 256 + threadIdx.x;
  if (i < DMc * DMc) WOb[i] = f2bf(WO[i]);
}

// ---------------- K1: gaussian basis * P + gamma  (f32 out) ------------------
// grid (H, NBL/128, 3proj), block 256 (4 waves) -> 1536 blocks = 6/CU uniform.
// wave w owns 8 d per half; lane handles rows (lane, lane+64) sharing params.
__global__ __launch_bounds__(256) void k1_gauss(
    const float* __restrict__ P, const float* __restrict__ t,
    const float* __restrict__ mu0, const float* __restrict__ al0, const float* __restrict__ w0, const float* __restrict__ gm0,
    const float* __restrict__ mu1, const float* __restrict__ al1, const float* __restrict__ w1, const float* __restrict__ gm1,
    const float* __restrict__ mu2, const float* __restrict__ al2, const float* __restrict__ w2, const float* __restrict__ gm2,
    float* __restrict__ o0, float* __restrict__ o1, float* __restrict__ o2)
{
  __shared__ float gbuf[32 * 129];           // [d-half][128 rows + pad]
  const int h = blockIdx.x, tile = blockIdx.y, p = blockIdx.z;
  const int tid = threadIdx.x, lane = tid & 63;
  const int wv = __builtin_amdgcn_readfirstlane(tid >> 6);   // wave-uniform in SGPR
  const int bl0 = tile * 128;

  const float* mu = (p == 0) ? mu0 : (p == 1) ? mu1 : mu2;
  const float* al = (p == 0) ? al0 : (p == 1) ? al1 : al2;
  const float* wp = (p == 0) ? w0  : (p == 1) ? w1  : w2;
  const float* gm = (p == 0) ? gm0 : (p == 1) ? gm1 : gm2;
  float*       op = (p == 0) ? o0  : (p == 1) ? o1  : o2;

  float ta[8], tb[8];
  {
    const float4 a0 = *(const float4*)&t[(size_t)(bl0 + lane) * 8];
    const float4 a1 = *(const float4*)&t[(size_t)(bl0 + lane) * 8 + 4];
    const float4 b0 = *(const float4*)&t[(size_t)(bl0 + 64 + lane) * 8];
    const float4 b1 = *(const float4*)&t[(size_t)(bl0 + 64 + lane) * 8 + 4];
    ta[0] = a0.x; ta[1] = a0.y; ta[2] = a0.z; ta[3] = a0.w;
    ta[4] = a1.x; ta[5] = a1.y; ta[6] = a1.z; ta[7] = a1.w;
    tb[0] = b0.x; tb[1] = b0.y; tb[2] = b0.z; tb[3] = b0.w;
    tb[4] = b1.x; tb[5] = b1.y; tb[6] = b1.z; tb[7] = b1.w;
  }

  #pragma unroll 1
  for (int half = 0; half < 2; ++half){
    #pragma unroll 2
    for (int dd = 0; dd < 8; ++dd){
      const int dloc = wv * 8 + dd;               // 0..31 within half
      const int d = half * 32 + dloc;
      const int base = (h * 64 + d) * 64;         // 64 (td,k) terms, wave-uniform -> s_load
      float ga0 = 0.f, ga1 = 0.f, gb0 = 0.f, gb1 = 0.f;
      #pragma unroll
      for (int td = 0; td < 8; ++td){
        const float tva = ta[td], tvb = tb[td];
        #pragma unroll
        for (int k = 0; k < 8; ++k){
          const int idx = base + td * 8 + k;
          const float m_ = mu[idx], a_ = al[idx], w_ = wp[idx];
          const float ua = (tva - m_) * a_;
          const float ub = (tvb - m_) * a_;
          const float ea = __builtin_amdgcn_exp2f(-(ua * ua));
          const float eb = __builtin_amdgcn_exp2f(-(ub * ub));
          if (k & 1){ ga1 = fmaf(w_, ea, ga1); gb1 = fmaf(w_, eb, gb1); }
          else      { ga0 = fmaf(w_, ea, ga0); gb0 = fmaf(w_, eb, gb0); }
        }
      }
      gbuf[dloc * 129 + lane]      = ga0 + ga1;
      gbuf[dloc * 129 + 64 + lane] = gb0 + gb1;
    }
    __syncthreads();

    { // transposed write: lanes = d (coalesced P read + output write)
      const int dl = tid & 31, rq = tid >> 5;    // rq in 0..7, 16 rows each
      const int dg = half * 32 + dl;
      const float gam = gm[h * 64 + dg];
      #pragma unroll 4
      for (int rr = 0; rr < 16; ++rr){
        const int r = rq * 16 + rr;
        const float g  = gbuf[dl * 129 + r];
        const float ph = P[(size_t)(bl0 + r) * DMc + h * 64 + dg];
        op[(size_t)(bl0 + r) * DMc + h * 64 + dg] = fmaf(g, ph, gam);
      }
    }
    __syncthreads();
  }
}

// ---------------- K2: per-head projection (f32, W-col in VGPRs, A via s_load) -
// grid (H, NBL/64), block 256.  PROJ 0=Q (f16 split, scaled log2e/8), 1=K (f16 split), 2=V (bf16 transposed)
template<int PROJ>
__global__ __launch_bounds__(256) void k2_proj(
    const float* __restrict__ Xg, const float* __restrict__ W,
    _Float16* __restrict__ Ohi, _Float16* __restrict__ Olo,
    unsigned short* __restrict__ Obf)
{
  __shared__ __align__(16) float Wl[64 * 64];
  const int h = blockIdx.x, tile = blockIdx.y, tid = threadIdx.x;
  const int bl0 = tile * 64;
  const int f = tid & 63;
  const int q = __builtin_amdgcn_readfirstlane(tid >> 6);  // wave-uniform row group

  for (int i = tid; i < 1024; i += 256){        // W[h]: 64 d x 64 f (f32)
    const int row = i >> 4, c4 = i & 15;
    *(float4*)&Wl[row * 64 + c4 * 4] =
        *(const float4*)&W[((size_t)h * 64 + row) * 64 + c4 * 4];
  }
  __syncthreads();

  float wcol[64];                               // this lane's W column
  #pragma unroll
  for (int d = 0; d < 64; ++d) wcol[d] = Wl[d * 64 + f];

  #pragma unroll 1
  for (int r = 0; r < 16; ++r){
    const int m = bl0 + q * 16 + r;             // flat (b,l), wave-uniform
    const float* ar = &Xg[(size_t)m * DMc + h * 64];   // uniform addr -> s_load
    float a0 = 0.f, a1 = 0.f, a2 = 0.f, a3 = 0.f;
    #pragma unroll
    for (int d = 0; d < 64; d += 4){
      a0 = fmaf(ar[d + 0], wcol[d + 0], a0);
      a1 = fmaf(ar[d + 1], wcol[d + 1], a1);
      a2 = fmaf(ar[d + 2], wcol[d + 2], a2);
      a3 = fmaf(ar[d + 3], wcol[d + 3], a3);
    }
    float acc = (a0 + a1) + (a2 + a3);

    const int b = m >> 10, l = m & 1023;
    if constexpr (PROJ == 0){
      acc *= 0.18033688011112042f;     // log2(e) / sqrt(D), folds softmax scale+base-2
      const _Float16 hi = (_Float16)acc;
      const _Float16 lo = (_Float16)(acc - (float)hi);
      const size_t o = (((size_t)b * Hc + h) * Lc + l) * 64 + f;
      Ohi[o] = hi; Olo[o] = lo;
    } else if constexpr (PROJ == 1){
      const _Float16 hi = (_Float16)acc;
      const _Float16 lo = (_Float16)(acc - (float)hi);
      const size_t o = (((size_t)b * Hc + h) * Lc + l) * 64 + (swz(l, f >> 3) << 3) + (f & 7);
      Ohi[o] = hi; Olo[o] = lo;
    } else {
      const int m0v = l & ~63, ml = l & 63;   // V transposed: [b][h][f][m]
      const size_t o = (((size_t)b * Hc + h) * 64 + f) * Lc + m0v + (swz(f, ml >> 3) << 3) + (ml & 7);
      Obf[o] = f2bf(acc);
    }
  }
}

// ---------------- K3: flash attention, f16-split QK^T + bf16 PV --------------
// grid (B*H, L/64), block 256 (4 waves, each owns 16 q-rows).
__global__ __launch_bounds__(256) void k3_attn(
    const _Float16* __restrict__ Qhi, const _Float16* __restrict__ Qlo,
    const _Float16* __restrict__ Khi, const _Float16* __restrict__ Klo,
    const unsigned short* __restrict__ Vt,
    unsigned short* __restrict__ AO)
{
  __shared__ __align__(16) _Float16 KhiL[64 * 64];
  __shared__ __align__(16) _Float16 KloL[64 * 64];
  __shared__ __align__(16) unsigned short VL[64 * 64];   // [f][m]
  __shared__ __align__(16) unsigned short PL[4][16 * 64];
  const int bh = blockIdx.x, qt = blockIdx.y;
  const int tid = threadIdx.x, wv = tid >> 6, lane = tid & 63;
  const int lrow = lane & 15, lgrp = lane >> 4;
  const size_t bhL = (size_t)bh * Lc;

  f16x8 qh[2], ql[2];
  {
    const int qrow = qt * 64 + wv * 16 + lrow;
    const _Float16* q1 = &Qhi[(bhL + qrow) * 64 + lgrp * 8];
    const _Float16* q2 = &Qlo[(bhL + qrow) * 64 + lgrp * 8];
    qh[0] = *(const f16x8*)q1; qh[1] = *(const f16x8*)(q1 + 32);
    ql[0] = *(const f16x8*)q2; ql[1] = *(const f16x8*)(q2 + 32);
  }

  f32x4 o[4] = {};
  float mrun[4], lrun[4];
  #pragma unroll
  for (int r = 0; r < 4; ++r){ mrun[r] = -1e30f; lrun[r] = 0.f; }

  for (int kt = 0; kt < 16; ++kt){
    __syncthreads();
    { // stage K hi/lo (contiguous 8KB; global layout is pre-swizzled) + V tile rows
      const char* ks_ = (const char*)(Khi + (bhL + kt * 64) * 64);
      const char* ls_ = (const char*)(Klo + (bhL + kt * 64) * 64);
      const char* vs_ = (const char*)(Vt + (size_t)bh * 64 * Lc + kt * 64);
      const int i0 = tid, i1 = tid + 256;
      f16x8 a0 = *(const f16x8*)(ks_ + i0 * 16);
      f16x8 a1 = *(const f16x8*)(ks_ + i1 * 16);
      f16x8 b0 = *(const f16x8*)(ls_ + i0 * 16);
      f16x8 b1 = *(const f16x8*)(ls_ + i1 * 16);
      s16x8 c0 = *(const s16x8*)(vs_ + (i0 >> 3) * 2048 + (i0 & 7) * 16);
      s16x8 c1 = *(const s16x8*)(vs_ + (i1 >> 3) * 2048 + (i1 & 7) * 16);
      *(f16x8*)((char*)KhiL + i0 * 16) = a0;
      *(f16x8*)((char*)KhiL + i1 * 16) = a1;
      *(f16x8*)((char*)KloL + i0 * 16) = b0;
      *(f16x8*)((char*)KloL + i1 * 16) = b1;
      *(s16x8*)((char*)VL + i0 * 16) = c0;
      *(s16x8*)((char*)VL + i1 * 16) = c1;
    }
    __syncthreads();

    // S = Q.K^T in exp2 domain (3-pass f16 split: hh + lh + hl)
    f32x4 s[4] = {};
    #pragma unroll
    for (int tt = 0; tt < 4; ++tt){
      #pragma unroll
      for (int ks = 0; ks < 2; ++ks){
        const int m = tt * 16 + lrow;
        const int off = m * 128 + swz(m, ks * 4 + lgrp) * 16;
        f16x8 kh_ = *(const f16x8*)((const char*)KhiL + off);
        f16x8 kl_ = *(const f16x8*)((const char*)KloL + off);
        s[tt] = __builtin_amdgcn_mfma_f32_16x16x32_f16(qh[ks], kh_, s[tt], 0, 0, 0);
        s[tt] = __builtin_amdgcn_mfma_f32_16x16x32_f16(ql[ks], kh_, s[tt], 0, 0, 0);
        s[tt] = __builtin_amdgcn_mfma_f32_16x16x32_f16(qh[ks], kl_, s[tt], 0, 0, 0);
      }
    }

    // online softmax (rows l = lgrp*4 + r ; m spread across 16 lanes x 4 tiles)
    float sc[4];
    #pragma unroll
    for (int r = 0; r < 4; ++r){
      float v = fmaxf(fmaxf(s[0][r], s[1][r]), fmaxf(s[2][r], s[3][r]));
      v = fmaxf(v, __shfl_xor(v, 1));
      v = fmaxf(v, __shfl_xor(v, 2));
      v = fmaxf(v, __shfl_xor(v, 4));
      v = fmaxf(v, __shfl_xor(v, 8));
      const float mn = fmaxf(mrun[r], v);
      sc[r] = exp2f(mrun[r] - mn);
      mrun[r] = mn;
    }
    float rs[4] = {0.f, 0.f, 0.f, 0.f};
    unsigned short pb[4][4];
    #pragma unroll
    for (int tt = 0; tt < 4; ++tt){
      #pragma unroll
      for (int r = 0; r < 4; ++r){
        const float p = exp2f(s[tt][r] - mrun[r]);
        rs[r] += p;
        pb[tt][r] = f2bf(p);
      }
    }
    #pragma unroll
    for (int r = 0; r < 4; ++r){
      float v = rs[r];
      v += __shfl_xor(v, 1); v += __shfl_xor(v, 2); v += __shfl_xor(v, 4); v += __shfl_xor(v, 8);
      lrun[r] = lrun[r] * sc[r] + v;
      o[0][r] *= sc[r]; o[1][r] *= sc[r]; o[2][r] *= sc[r]; o[3][r] *= sc[r];
    }

    // P -> per-wave LDS (bf16), then PV MFMA (no barrier needed: wave-private)
    unsigned short* pw = (unsigned short*)PL[wv];
    #pragma unroll
    for (int tt = 0; tt < 4; ++tt){
      const int m = tt * 16 + lrow;
      #pragma unroll
      for (int r = 0; r < 4; ++r){
        const int l = lgrp * 4 + r;
        *(unsigned short*)((char*)pw + l * 128 + swz(l, m >> 3) * 16 + (m & 7) * 2) = pb[tt][r];
      }
    }
    #pragma unroll
    for (int ks = 0; ks < 2; ++ks){
      const int poff = lrow * 128 + swz(lrow, ks * 4 + lgrp) * 16;
      s16x8 pa = *(const s16x8*)((const char*)pw + poff);
      #pragma unroll
      for (int t2 = 0; t2 < 4; ++t2){
        const int f = t2 * 16 + lrow;
        const int voff = f * 128 + swz(f, ks * 4 + lgrp) * 16;
        s16x8 vb = *(const s16x8*)((const char*)VL + voff);
        o[t2] = __builtin_amdgcn_mfma_f32_16x16x32_bf16(pa, vb, o[t2], 0, 0, 0);
      }
    }
  }

  const int b = bh >> 4, hh = bh & 15;
  #pragma unroll
  for (int r = 0; r < 4; ++r){
    const float inv = 1.0f / lrun[r];
    const int l = qt * 64 + wv * 16 + lgrp * 4 + r;
    #pragma unroll
    for (int t2 = 0; t2 < 4; ++t2){
      const int f = t2 * 16 + lrow;
      AO[((size_t)(b * Lc + l)) * DMc + hh * 64 + f] = f2bf(o[t2][r] * inv);
    }
  }
}

// ---------------- K4: out = attn @ W_O^T + b  (bf16 MFMA GEMM, f32 out) ------
// grid (NBL/128, DM/128), block 256 (2x2 waves, each 64x64).
__global__ __launch_bounds__(256) void k4_out(
    const unsigned short* __restrict__ A, const unsigned short* __restrict__ Bw,
    const float* __restrict__ bias, float* __restrict__ out)
{
  __shared__ __align__(16) unsigned short Asl[128 * 64];
  __shared__ __align__(16) unsigned short Bsl[128 * 64];
  const int mt = blockIdx.x, nt = blockIdx.y;
  const int tid = threadIdx.x, wv = tid >> 6, lane = tid & 63;
  const int wr = wv >> 1, wc = wv & 1, lrow = lane & 15, lgrp = lane >> 4;
  f32x4 acc[4][4] = {};
  const char* abase = (const char*)A  + (size_t)mt * 128 * 2048;
  const char* bbase = (const char*)Bw + (size_t)nt * 128 * 2048;

  for (int kt = 0; kt < 16; ++kt){
    __syncthreads();
    #pragma unroll
    for (int q = 0; q < 4; ++q){
      const int i = q * 256 + tid, row = i >> 3, u = i & 7;
      s16x8 av = *(const s16x8*)(abase + (size_t)row * 2048 + kt * 128 + u * 16);
      s16x8 bv = *(const s16x8*)(bbase + (size_t)row * 2048 + kt * 128 + u * 16);
      *(s16x8*)((char*)Asl + row * 128 + swz(row, u) * 16) = av;
      *(s16x8*)((char*)Bsl + row * 128 + swz(row, u) * 16) = bv;
    }
    __syncthreads();
    #pragma unroll
    for (int ks = 0; ks < 2; ++ks){
      s16x8 af[4], bf[4];
      #pragma unroll
      for (int i4 = 0; i4 < 4; ++i4){
        const int row = wr * 64 + i4 * 16 + lrow;
        af[i4] = *(const s16x8*)((const char*)Asl + row * 128 + swz(row, ks * 4 + lgrp) * 16);
        const int col = wc * 64 + i4 * 16 + lrow;
        bf[i4] = *(const s16x8*)((const char*)Bsl + col * 128 + swz(col, ks * 4 + lgrp) * 16);
      }
      #pragma unroll
      for (int i4 = 0; i4 < 4; ++i4)
        #pragma unroll
        for (int j4 = 0; j4 < 4; ++j4)
          acc[i4][j4] = __builtin_amdgcn_mfma_f32_16x16x32_bf16(af[i4], bf[j4], acc[i4][j4], 0, 0, 0);
    }
  }
  #pragma unroll
  for (int i4 = 0; i4 < 4; ++i4)
    #pragma unroll
    for (int j4 = 0; j4 < 4; ++j4){
      const int col = nt * 128 + wc * 64 + j4 * 16 + lrow;
      const float bb = bias[col];
      #pragma unroll
      for (int r = 0; r < 4; ++r){
        const int row = mt * 128 + wr * 64 + i4 * 16 + lgrp * 4 + r;
        out[(size_t)row * DMc + col] = acc[i4][j4][r] + bb;
      }
    }
}

// ---------------- launch -----------------------------------------------------
extern "C" void kernel_launch(void* const* d_in, const int* in_sizes, int n_in,
                              void* d_out, int out_size, void* d_ws, size_t ws_size,
                              hipStream_t stream)
{
  const float* P   = (const float*)d_in[0];
  const float* t   = (const float*)d_in[1];
  const float* muQ = (const float*)d_in[2];
  const float* sgQ = (const float*)d_in[3];
  const float* wQ  = (const float*)d_in[4];
  const float* gQ  = (const float*)d_in[5];
  const float* WQ  = (const float*)d_in[6];
  const float* muK = (const float*)d_in[7];
  const float* sgK = (const float*)d_in[8];
  const float* wK  = (const float*)d_in[9];
  const float* gK  = (const float*)d_in[10];
  const float* WK  = (const float*)d_in[11];
  const float* muV = (const float*)d_in[12];
  const float* sgV = (const float*)d_in[13];
  const float* wV  = (const float*)d_in[14];
  const float* gV  = (const float*)d_in[15];
  const float* WV  = (const float*)d_in[16];
  const float* WO  = (const float*)d_in[17];
  const float* WOb = (const float*)d_in[18];

  char* w = (char*)d_ws;
  auto take = [&](size_t bytes) -> char* {
    char* p = w; w += (bytes + 255) & ~(size_t)255; return p;
  };
  float* aQ = (float*)take((size_t)PAR * 4);
  float* aK = (float*)take((size_t)PAR * 4);
  float* aV = (float*)take((size_t)PAR * 4);
  float* Qg = (float*)take((size_t)NBL * DMc * 4);
  float* Kg = (float*)take((size_t)NBL * DMc * 4);
  float* Vg = (float*)take((size_t)NBL * DMc * 4);
  _Float16* Qhi = (_Float16*)take((size_t)NBL * DMc * 2);
  _Float16* Qlo = (_Float16*)take((size_t)NBL * DMc * 2);
  _Float16* Khi = (_Float16*)take((size_t)NBL * DMc * 2);
  _Float16* Klo = (_Float16*)take((size_t)NBL * DMc * 2);
  unsigned short* Vt    = (unsigned short*)take((size_t)NBL * DMc * 2);
  unsigned short* AO    = (unsigned short*)take((size_t)NBL * DMc * 2);
  unsigned short* WOb16 = (unsigned short*)take((size_t)DMc * DMc * 2);
  if ((size_t)(w - (char*)d_ws) > ws_size) return;  // insufficient scratch: bail

  k0_alpha<<<PAR / 256, 256, 0, stream>>>(sgQ, sgK, sgV, aQ, aK, aV);
  k0_wo<<<DMc * DMc / 256, 256, 0, stream>>>(WO, WOb16);
  k1_gauss<<<dim3(Hc, NBL / 128, 3), 256, 0, stream>>>(P, t,
      muQ, aQ, wQ, gQ,  muK, aK, wK, gK,  muV, aV, wV, gV,  Qg, Kg, Vg);
  k2_proj<0><<<dim3(Hc, NBL / 64), 256, 0, stream>>>(Qg, WQ, Qhi, Qlo, nullptr);
  k2_proj<1><<<dim3(Hc, NBL / 64), 256, 0, stream>>>(Kg, WK, Khi, Klo, nullptr);
  k2_proj<2><<<dim3(Hc, NBL / 64), 256, 0, stream>>>(Vg, WV, nullptr, nullptr, Vt);
  k3_attn<<<dim3(Bc * Hc, Lc / 64), 256, 0, stream>>>(Qhi, Qlo, Khi, Klo, Vt, AO);
  k4_out<<<dim3(NBL / 128, DMc / 128), 256, 0, stream>>>(AO, WOb16, WOb, (float*)d_out);
}

// Round 6
// 322.599 us; speedup vs baseline: 3.5461x; 1.0836x over previous
//
#include <hip/hip_runtime.h>
#include <cstdint>

#define DEVI __device__ __forceinline__

constexpr int Bc = 4, Lc = 1024, DMc = 1024, Hc = 16, TDc = 8, Kc = 8, Dc = 64;
constexpr int NBL = Bc * Lc;               // 4096
constexpr int PAR = Hc * Dc * TDc * Kc;    // 65536 per param array

using f16x8 = __attribute__((ext_vector_type(8))) _Float16;
using s16x8 = __attribute__((ext_vector_type(8))) short;
using f32x4 = __attribute__((ext_vector_type(4))) float;

DEVI unsigned short f2bf(float x){
  union { float f; unsigned u; } v; v.f = x;
  return (unsigned short)((v.u + 0x7fffu + ((v.u >> 16) & 1u)) >> 16);
}

// LDS swizzle — ON (r4 showed ~15us net gain in k2/k3/k4; write/read pairs audited r0).
#define SWZ_ON 1
DEVI int swz(int row, int unit){
#if SWZ_ON
  return unit ^ (row & 7);
#else
  (void)row; return unit;
#endif
}

// ---------------- K0: precompute alpha = sqrt(log2e/2)/sigma ; WO -> bf16 ----
__global__ __launch_bounds__(256) void k0_alpha(
    const float* __restrict__ sQ, const float* __restrict__ sK, const float* __restrict__ sV,
    float* __restrict__ aQ, float* __restrict__ aK, float* __restrict__ aV)
{
  int i = blockIdx.x * 256 + threadIdx.x;
  if (i < PAR){
    const float c = 0.8493218002880191f; // sqrt(log2(e)/2)
    aQ[i] = c / sQ[i];
    aK[i] = c / sK[i];
    aV[i] = c / sV[i];
  }
}

__global__ __launch_bounds__(256) void k0_wo(const float* __restrict__ WO, unsigned short* __restrict__ WOb)
{
  int i = blockIdx.x * 256 + threadIdx.x;
  if (i < DMc * DMc) WOb[i] = f2bf(WO[i]);
}

// ---------------- K1: gaussian basis * P + gamma  (f32 out) ------------------
// r3 structure (measured 143us): grid (H, NBL/64, 3proj), block 256 (4 waves).
__global__ __launch_bounds__(256) void k1_gauss(
    const float* __restrict__ P, const float* __restrict__ t,
    const float* __restrict__ mu0, const float* __restrict__ al0, const float* __restrict__ w0, const float* __restrict__ gm0,
    const float* __restrict__ mu1, const float* __restrict__ al1, const float* __restrict__ w1, const float* __restrict__ gm1,
    const float* __restrict__ mu2, const float* __restrict__ al2, const float* __restrict__ w2, const float* __restrict__ gm2,
    float* __restrict__ o0, float* __restrict__ o1, float* __restrict__ o2)
{
  __shared__ float gbuf[64 * 65];
  const int h = blockIdx.x, tile = blockIdx.y, p = blockIdx.z;
  const int tid = threadIdx.x, lane = tid & 63;
  const int wv = __builtin_amdgcn_readfirstlane(tid >> 6);   // wave-uniform in SGPR
  const int bl0 = tile * 64;

  const float* mu = (p == 0) ? mu0 : (p == 1) ? mu1 : mu2;
  const float* al = (p == 0) ? al0 : (p == 1) ? al1 : al2;
  const float* wp = (p == 0) ? w0  : (p == 1) ? w1  : w2;
  const float* gm = (p == 0) ? gm0 : (p == 1) ? gm1 : gm2;
  float*       op = (p == 0) ? o0  : (p == 1) ? o1  : o2;

  float tv[8];
  {
    const float4 t0 = *(const float4*)&t[(size_t)(bl0 + lane) * 8];
    const float4 t1 = *(const float4*)&t[(size_t)(bl0 + lane) * 8 + 4];
    tv[0] = t0.x; tv[1] = t0.y; tv[2] = t0.z; tv[3] = t0.w;
    tv[4] = t1.x; tv[5] = t1.y; tv[6] = t1.z; tv[7] = t1.w;
  }

  #pragma unroll 2
  for (int dd = 0; dd < 16; ++dd){
    const int d = wv * 16 + dd;
    const int base = (h * 64 + d) * 64;   // 64 (td,k) terms, wave-uniform -> s_load
    float g0 = 0.f, g1 = 0.f, g2 = 0.f, g3 = 0.f;
    #pragma unroll
    for (int td = 0; td < 8; ++td){
      const float tval = tv[td];
      #pragma unroll
      for (int k = 0; k < 8; ++k){
        const int idx = base + td * 8 + k;
        const float u = (tval - mu[idx]) * al[idx];   // 2^(-u^2) == exp(-(t-mu)^2/(2s^2))
        const float e = __builtin_amdgcn_exp2f(-(u * u));
        if ((k & 3) == 0)      g0 = fmaf(wp[idx], e, g0);
        else if ((k & 3) == 1) g1 = fmaf(wp[idx], e, g1);
        else if ((k & 3) == 2) g2 = fmaf(wp[idx], e, g2);
        else                   g3 = fmaf(wp[idx], e, g3);
      }
    }
    gbuf[d * 65 + lane] = (g0 + g1) + (g2 + g3);
  }
  __syncthreads();

  { // transposed write phase: lanes = d (coalesced P read + output write)
    const int dl = tid & 63, rq = tid >> 6;
    const float gam = gm[h * 64 + dl];
    #pragma unroll 4
    for (int rr = 0; rr < 16; ++rr){
      const int r = rq * 16 + rr;
      const float g  = gbuf[dl * 65 + r];
      const float ph = P[(size_t)(bl0 + r) * DMc + h * 64 + dl];
      op[(size_t)(bl0 + r) * DMc + h * 64 + dl] = fmaf(g, ph, gam);
    }
  }
}

// ---------------- K2: per-head projection (f32, W-col in VGPRs, A via s_load) -
// grid (H, NBL/64), block 256.  PROJ 0=Q (f16 split, scaled log2e/8), 1=K (f16 split), 2=V (bf16 transposed)
template<int PROJ>
__global__ __launch_bounds__(256) void k2_proj(
    const float* __restrict__ Xg, const float* __restrict__ W,
    _Float16* __restrict__ Ohi, _Float16* __restrict__ Olo,
    unsigned short* __restrict__ Obf)
{
  __shared__ __align__(16) float Wl[64 * 64];
  const int h = blockIdx.x, tile = blockIdx.y, tid = threadIdx.x;
  const int bl0 = tile * 64;
  const int f = tid & 63;
  const int q = __builtin_amdgcn_readfirstlane(tid >> 6);  // wave-uniform row group

  for (int i = tid; i < 1024; i += 256){        // W[h]: 64 d x 64 f (f32)
    const int row = i >> 4, c4 = i & 15;
    *(float4*)&Wl[row * 64 + c4 * 4] =
        *(const float4*)&W[((size_t)h * 64 + row) * 64 + c4 * 4];
  }
  __syncthreads();

  float wcol[64];                               // this lane's W column
  #pragma unroll
  for (int d = 0; d < 64; ++d) wcol[d] = Wl[d * 64 + f];

  #pragma unroll 1
  for (int r = 0; r < 16; ++r){
    const int m = bl0 + q * 16 + r;             // flat (b,l), wave-uniform
    const float* ar = &Xg[(size_t)m * DMc + h * 64];   // uniform addr -> s_load
    float a0 = 0.f, a1 = 0.f, a2 = 0.f, a3 = 0.f;
    #pragma unroll
    for (int d = 0; d < 64; d += 4){
      a0 = fmaf(ar[d + 0], wcol[d + 0], a0);
      a1 = fmaf(ar[d + 1], wcol[d + 1], a1);
      a2 = fmaf(ar[d + 2], wcol[d + 2], a2);
      a3 = fmaf(ar[d + 3], wcol[d + 3], a3);
    }
    float acc = (a0 + a1) + (a2 + a3);

    const int b = m >> 10, l = m & 1023;
    if constexpr (PROJ == 0){
      acc *= 0.18033688011112042f;     // log2(e) / sqrt(D), folds softmax scale+base-2
      const _Float16 hi = (_Float16)acc;
      const _Float16 lo = (_Float16)(acc - (float)hi);
      const size_t o = (((size_t)b * Hc + h) * Lc + l) * 64 + f;
      Ohi[o] = hi; Olo[o] = lo;
    } else if constexpr (PROJ == 1){
      const _Float16 hi = (_Float16)acc;
      const _Float16 lo = (_Float16)(acc - (float)hi);
      const size_t o = (((size_t)b * Hc + h) * Lc + l) * 64 + (swz(l, f >> 3) << 3) + (f & 7);
      Ohi[o] = hi; Olo[o] = lo;
    } else {
      const int m0v = l & ~63, ml = l & 63;   // V transposed: [b][h][f][m]
      const size_t o = (((size_t)b * Hc + h) * 64 + f) * Lc + m0v + (swz(f, ml >> 3) << 3) + (ml & 7);
      Obf[o] = f2bf(acc);
    }
  }
}

// ---------------- K3: flash attention, f16-split QK^T + bf16 PV --------------
// grid (B*H, L/64), block 256 (4 waves, each owns 16 q-rows).
__global__ __launch_bounds__(256) void k3_attn(
    const _Float16* __restrict__ Qhi, const _Float16* __restrict__ Qlo,
    const _Float16* __restrict__ Khi, const _Float16* __restrict__ Klo,
    const unsigned short* __restrict__ Vt,
    unsigned short* __restrict__ AO)
{
  __shared__ __align__(16) _Float16 KhiL[64 * 64];
  __shared__ __align__(16) _Float16 KloL[64 * 64];
  __shared__ __align__(16) unsigned short VL[64 * 64];   // [f][m]
  __shared__ __align__(16) unsigned short PL[4][16 * 64];
  const int bh = blockIdx.x, qt = blockIdx.y;
  const int tid = threadIdx.x, wv = tid >> 6, lane = tid & 63;
  const int lrow = lane & 15, lgrp = lane >> 4;
  const size_t bhL = (size_t)bh * Lc;

  f16x8 qh[2], ql[2];
  {
    const int qrow = qt * 64 + wv * 16 + lrow;
    const _Float16* q1 = &Qhi[(bhL + qrow) * 64 + lgrp * 8];
    const _Float16* q2 = &Qlo[(bhL + qrow) * 64 + lgrp * 8];
    qh[0] = *(const f16x8*)q1; qh[1] = *(const f16x8*)(q1 + 32);
    ql[0] = *(const f16x8*)q2; ql[1] = *(const f16x8*)(q2 + 32);
  }

  f32x4 o[4] = {};
  float mrun[4], lrun[4];
  #pragma unroll
  for (int r = 0; r < 4; ++r){ mrun[r] = -1e30f; lrun[r] = 0.f; }

  for (int kt = 0; kt < 16; ++kt){
    __syncthreads();
    { // stage K hi/lo (contiguous 8KB; global layout is pre-swizzled) + V tile rows
      const char* ks_ = (const char*)(Khi + (bhL + kt * 64) * 64);
      const char* ls_ = (const char*)(Klo + (bhL + kt * 64) * 64);
      const char* vs_ = (const char*)(Vt + (size_t)bh * 64 * Lc + kt * 64);
      const int i0 = tid, i1 = tid + 256;
      f16x8 a0 = *(const f16x8*)(ks_ + i0 * 16);
      f16x8 a1 = *(const f16x8*)(ks_ + i1 * 16);
      f16x8 b0 = *(const f16x8*)(ls_ + i0 * 16);
      f16x8 b1 = *(const f16x8*)(ls_ + i1 * 16);
      s16x8 c0 = *(const s16x8*)(vs_ + (i0 >> 3) * 2048 + (i0 & 7) * 16);
      s16x8 c1 = *(const s16x8*)(vs_ + (i1 >> 3) * 2048 + (i1 & 7) * 16);
      *(f16x8*)((char*)KhiL + i0 * 16) = a0;
      *(f16x8*)((char*)KhiL + i1 * 16) = a1;
      *(f16x8*)((char*)KloL + i0 * 16) = b0;
      *(f16x8*)((char*)KloL + i1 * 16) = b1;
      *(s16x8*)((char*)VL + i0 * 16) = c0;
      *(s16x8*)((char*)VL + i1 * 16) = c1;
    }
    __syncthreads();

    // S = Q.K^T in exp2 domain (3-pass f16 split: hh + lh + hl)
    f32x4 s[4] = {};
    #pragma unroll
    for (int tt = 0; tt < 4; ++tt){
      #pragma unroll
      for (int ks = 0; ks < 2; ++ks){
        const int m = tt * 16 + lrow;
        const int off = m * 128 + swz(m, ks * 4 + lgrp) * 16;
        f16x8 kh_ = *(const f16x8*)((const char*)KhiL + off);
        f16x8 kl_ = *(const f16x8*)((const char*)KloL + off);
        s[tt] = __builtin_amdgcn_mfma_f32_16x16x32_f16(qh[ks], kh_, s[tt], 0, 0, 0);
        s[tt] = __builtin_amdgcn_mfma_f32_16x16x32_f16(ql[ks], kh_, s[tt], 0, 0, 0);
        s[tt] = __builtin_amdgcn_mfma_f32_16x16x32_f16(qh[ks], kl_, s[tt], 0, 0, 0);
      }
    }

    // online softmax (rows l = lgrp*4 + r ; m spread across 16 lanes x 4 tiles)
    float sc[4];
    #pragma unroll
    for (int r = 0; r < 4; ++r){
      float v = fmaxf(fmaxf(s[0][r], s[1][r]), fmaxf(s[2][r], s[3][r]));
      v = fmaxf(v, __shfl_xor(v, 1));
      v = fmaxf(v, __shfl_xor(v, 2));
      v = fmaxf(v, __shfl_xor(v, 4));
      v = fmaxf(v, __shfl_xor(v, 8));
      const float mn = fmaxf(mrun[r], v);
      sc[r] = __builtin_amdgcn_exp2f(mrun[r] - mn);   // arg <= 0, raw v_exp_f32 safe
      mrun[r] = mn;
    }
    float rs[4] = {0.f, 0.f, 0.f, 0.f};
    unsigned short pb[4][4];
    #pragma unroll
    for (int tt = 0; tt < 4; ++tt){
      #pragma unroll
      for (int r = 0; r < 4; ++r){
        const float p = __builtin_amdgcn_exp2f(s[tt][r] - mrun[r]);  // arg <= 0
        rs[r] += p;
        pb[tt][r] = f2bf(p);
      }
    }
    #pragma unroll
    for (int r = 0; r < 4; ++r){
      float v = rs[r];
      v += __shfl_xor(v, 1); v += __shfl_xor(v, 2); v += __shfl_xor(v, 4); v += __shfl_xor(v, 8);
      lrun[r] = lrun[r] * sc[r] + v;
      o[0][r] *= sc[r]; o[1][r] *= sc[r]; o[2][r] *= sc[r]; o[3][r] *= sc[r];
    }

    // P -> per-wave LDS (bf16), then PV MFMA (wave-private buffer).
    short* pw = (short*)PL[wv];
    #pragma unroll
    for (int tt = 0; tt < 4; ++tt){
      const int m = tt * 16 + lrow;
      #pragma unroll
      for (int r = 0; r < 4; ++r){
        const int l = lgrp * 4 + r;
        *(short*)((char*)pw + l * 128 + swz(l, m >> 3) * 16 + (m & 7) * 2) = (short)pb[tt][r];
      }
    }
    // HARD ORDER: the 16 ds_write_b16 above vs the ds_read_b128 below are a
    // mixed-type same-address pair the compiler's AA may not order (rule #18
    // class hazard; r5 post-timing divergence). Force wait + pin schedule.
    asm volatile("s_waitcnt lgkmcnt(0)" ::: "memory");
    __builtin_amdgcn_sched_barrier(0);
    #pragma unroll
    for (int ks = 0; ks < 2; ++ks){
      const int poff = lrow * 128 + swz(lrow, ks * 4 + lgrp) * 16;
      s16x8 pa = *(const s16x8*)((const char*)pw + poff);
      #pragma unroll
      for (int t2 = 0; t2 < 4; ++t2){
        const int f = t2 * 16 + lrow;
        const int voff = f * 128 + swz(f, ks * 4 + lgrp) * 16;
        s16x8 vb = *(const s16x8*)((const char*)VL + voff);
        o[t2] = __builtin_amdgcn_mfma_f32_16x16x32_bf16(pa, vb, o[t2], 0, 0, 0);
      }
    }
  }

  const int b = bh >> 4, hh = bh & 15;
  #pragma unroll
  for (int r = 0; r < 4; ++r){
    const float inv = 1.0f / lrun[r];
    const int l = qt * 64 + wv * 16 + lgrp * 4 + r;
    #pragma unroll
    for (int t2 = 0; t2 < 4; ++t2){
      const int f = t2 * 16 + lrow;
      AO[((size_t)(b * Lc + l)) * DMc + hh * 64 + f] = f2bf(o[t2][r] * inv);
    }
  }
}

// ---------------- K4: out = attn @ W_O^T + b  (bf16 MFMA GEMM, f32 out) ------
// grid (NBL/128, DM/128), block 256 (2x2 waves, each 64x64).
__global__ __launch_bounds__(256) void k4_out(
    const unsigned short* __restrict__ A, const unsigned short* __restrict__ Bw,
    const float* __restrict__ bias, float* __restrict__ out)
{
  __shared__ __align__(16) unsigned short Asl[128 * 64];
  __shared__ __align__(16) unsigned short Bsl[128 * 64];
  const int mt = blockIdx.x, nt = blockIdx.y;
  const int tid = threadIdx.x, wv = tid >> 6, lane = tid & 63;
  const int wr = wv >> 1, wc = wv & 1, lrow = lane & 15, lgrp = lane >> 4;
  f32x4 acc[4][4] = {};
  const char* abase = (const char*)A  + (size_t)mt * 128 * 2048;
  const char* bbase = (const char*)Bw + (size_t)nt * 128 * 2048;

  for (int kt = 0; kt < 16; ++kt){
    __syncthreads();
    #pragma unroll
    for (int q = 0; q < 4; ++q){
      const int i = q * 256 + tid, row = i >> 3, u = i & 7;
      s16x8 av = *(const s16x8*)(abase + (size_t)row * 2048 + kt * 128 + u * 16);
      s16x8 bv = *(const s16x8*)(bbase + (size_t)row * 2048 + kt * 128 + u * 16);
      *(s16x8*)((char*)Asl + row * 128 + swz(row, u) * 16) = av;
      *(s16x8*)((char*)Bsl + row * 128 + swz(row, u) * 16) = bv;
    }
    __syncthreads();
    #pragma unroll
    for (int ks = 0; ks < 2; ++ks){
      s16x8 af[4], bf[4];
      #pragma unroll
      for (int i4 = 0; i4 < 4; ++i4){
        const int row = wr * 64 + i4 * 16 + lrow;
        af[i4] = *(const s16x8*)((const char*)Asl + row * 128 + swz(row, ks * 4 + lgrp) * 16);
        const int col = wc * 64 + i4 * 16 + lrow;
        bf[i4] = *(const s16x8*)((const char*)Bsl + col * 128 + swz(col, ks * 4 + lgrp) * 16);
      }
      #pragma unroll
      for (int i4 = 0; i4 < 4; ++i4)
        #pragma unroll
        for (int j4 = 0; j4 < 4; ++j4)
          acc[i4][j4] = __builtin_amdgcn_mfma_f32_16x16x32_bf16(af[i4], bf[j4], acc[i4][j4], 0, 0, 0);
    }
  }
  #pragma unroll
  for (int i4 = 0; i4 < 4; ++i4)
    #pragma unroll
    for (int j4 = 0; j4 < 4; ++j4){
      const int col = nt * 128 + wc * 64 + j4 * 16 + lrow;
      const float bb = bias[col];
      #pragma unroll
      for (int r = 0; r < 4; ++r){
        const int row = mt * 128 + wr * 64 + i4 * 16 + lgrp * 4 + r;
        out[(size_t)row * DMc + col] = acc[i4][j4][r] + bb;
      }
    }
}

// ---------------- launch -----------------------------------------------------
extern "C" void kernel_launch(void* const* d_in, const int* in_sizes, int n_in,
                              void* d_out, int out_size, void* d_ws, size_t ws_size,
                              hipStream_t stream)
{
  const float* P   = (const float*)d_in[0];
  const float* t   = (const float*)d_in[1];
  const float* muQ = (const float*)d_in[2];
  const float* sgQ = (const float*)d_in[3];
  const float* wQ  = (const float*)d_in[4];
  const float* gQ  = (const float*)d_in[5];
  const float* WQ  = (const float*)d_in[6];
  const float* muK = (const float*)d_in[7];
  const float* sgK = (const float*)d_in[8];
  const float* wK  = (const float*)d_in[9];
  const float* gK  = (const float*)d_in[10];
  const float* WK  = (const float*)d_in[11];
  const float* muV = (const float*)d_in[12];
  const float* sgV = (const float*)d_in[13];
  const float* wV  = (const float*)d_in[14];
  const float* gV  = (const float*)d_in[15];
  const float* WV  = (const float*)d_in[16];
  const float* WO  = (const float*)d_in[17];
  const float* WOb = (const float*)d_in[18];

  char* w = (char*)d_ws;
  auto take = [&](size_t bytes) -> char* {
    char* p = w; w += (bytes + 255) & ~(size_t)255; return p;
  };
  float* aQ = (float*)take((size_t)PAR * 4);
  float* aK = (float*)take((size_t)PAR * 4);
  float* aV = (float*)take((size_t)PAR * 4);
  float* Qg = (float*)take((size_t)NBL * DMc * 4);
  float* Kg = (float*)take((size_t)NBL * DMc * 4);
  float* Vg = (float*)take((size_t)NBL * DMc * 4);
  _Float16* Qhi = (_Float16*)take((size_t)NBL * DMc * 2);
  _Float16* Qlo = (_Float16*)take((size_t)NBL * DMc * 2);
  _Float16* Khi = (_Float16*)take((size_t)NBL * DMc * 2);
  _Float16* Klo = (_Float16*)take((size_t)NBL * DMc * 2);
  unsigned short* Vt    = (unsigned short*)take((size_t)NBL * DMc * 2);
  unsigned short* AO    = (unsigned short*)take((size_t)NBL * DMc * 2);
  unsigned short* WOb16 = (unsigned short*)take((size_t)DMc * DMc * 2);
  if ((size_t)(w - (char*)d_ws) > ws_size) return;  // insufficient scratch: bail

  k0_alpha<<<PAR / 256, 256, 0, stream>>>(sgQ, sgK, sgV, aQ, aK, aV);
  k0_wo<<<DMc * DMc / 256, 256, 0, stream>>>(WO, WOb16);
  k1_gauss<<<dim3(Hc, NBL / 64, 3), 256, 0, stream>>>(P, t,
      muQ, aQ, wQ, gQ,  muK, aK, wK, gK,  muV, aV, wV, gV,  Qg, Kg, Vg);
  k2_proj<0><<<dim3(Hc, NBL / 64), 256, 0, stream>>>(Qg, WQ, Qhi, Qlo, nullptr);
  k2_proj<1><<<dim3(Hc, NBL / 64), 256, 0, stream>>>(Kg, WK, Khi, Klo, nullptr);
  k2_proj<2><<<dim3(Hc, NBL / 64), 256, 0, stream>>>(Vg, WV, nullptr, nullptr, Vt);
  k3_attn<<<dim3(Bc * Hc, Lc / 64), 256, 0, stream>>>(Qhi, Qlo, Khi, Klo, Vt, AO);
  k4_out<<<dim3(NBL / 128, DMc / 128), 256, 0, stream>>>(AO, WOb16, WOb, (float*)d_out);
}